// Round 1
// baseline (1349.444 us; speedup 1.0000x reference)
//
#include <hip/hip_runtime.h>

typedef unsigned short u16;
typedef unsigned int   u32;
typedef __attribute__((ext_vector_type(8))) __bf16 bf16x8;
typedef __attribute__((ext_vector_type(4))) float  f32x4;

#define LOG2E 1.44269504088896340f

__device__ __forceinline__ u16 f2bf(float x) {
  u32 u = __float_as_uint(x);
  u32 r = u + 0x7fffu + ((u >> 16) & 1u);
  return (u16)(r >> 16);
}
__device__ __forceinline__ float bf2f(u16 h) {
  return __uint_as_float(((u32)h) << 16);
}
__device__ __forceinline__ void gload16(const u16* g, u16* l) {
  __builtin_amdgcn_global_load_lds(
      (const __attribute__((address_space(1))) void*)g,
      (__attribute__((address_space(3))) void*)l, 16, 0, 0);
}
__device__ __forceinline__ f32x4 MFMA(bf16x8 a, bf16x8 b, f32x4 c) {
  return __builtin_amdgcn_mfma_f32_16x16x32_bf16(a, b, c, 0, 0, 0);
}
__device__ __forceinline__ float rmax16(float x) {
  x = fmaxf(x, __shfl_xor(x, 1));
  x = fmaxf(x, __shfl_xor(x, 2));
  x = fmaxf(x, __shfl_xor(x, 4));
  x = fmaxf(x, __shfl_xor(x, 8));
  return x;
}
__device__ __forceinline__ float rsum16(float x) {
  x += __shfl_xor(x, 1);
  x += __shfl_xor(x, 2);
  x += __shfl_xor(x, 4);
  x += __shfl_xor(x, 8);
  return x;
}

// ---------------- elementwise fp32 -> bf16 hi/lo split ----------------
__global__ void conv_split(const float4* __restrict__ src,
                           u16* __restrict__ dh, u16* __restrict__ dl, int n4) {
  int i = blockIdx.x * 256 + threadIdx.x;
  if (i >= n4) return;
  float4 v = src[i];
  float a[4] = {v.x, v.y, v.z, v.w};
  union { u16 u[4]; uint2 q; } H, L;
#pragma unroll
  for (int k = 0; k < 4; ++k) {
    u16 hh = f2bf(a[k]);
    H.u[k] = hh;
    L.u[k] = f2bf(a[k] - bf2f(hh));
  }
  *(uint2*)&dh[(size_t)i * 4] = H.q;
  *(uint2*)&dl[(size_t)i * 4] = L.q;
}

// ---------------- transpose [K x N] fp32 -> [N x 2048] bf16 hi/lo ----------------
__global__ void transpose_split(const float* __restrict__ src, int K, int N,
                                u16* __restrict__ dh, u16* __restrict__ dl,
                                int rowOff) {
  __shared__ float t[32][33];
  int n0 = blockIdx.x * 32, k0 = blockIdx.y * 32;
  int tx = threadIdx.x, ty = threadIdx.y;
#pragma unroll
  for (int i = 0; i < 4; ++i)
    t[ty + 8 * i][tx] = src[(size_t)(k0 + ty + 8 * i) * N + n0 + tx];
  __syncthreads();
#pragma unroll
  for (int i = 0; i < 4; ++i) {
    int n = n0 + ty + 8 * i, k = k0 + tx;
    float v = t[tx][ty + 8 * i];
    u16 hh = f2bf(v);
    size_t o = (size_t)(rowOff + n) * 2048 + k;
    dh[o] = hh;
    dl[o] = f2bf(v - bf2f(hh));
  }
}

// ---------------- split-bf16 GEMM: C = A(hi+lo) * B(hi+lo)^T ----------------
// A [M x K] row-major (hi/lo), B given transposed [N x K] row-major (hi/lo).
// MODE 0: QKV epilogue (writes Qhi/Qlo, Khi/Klo, VT-bf16), MODE 1: out-proj (fp32 + bias)
template <int MODE>
__global__ __launch_bounds__(256) void gemm_split(
    const u16* __restrict__ Ah, const u16* __restrict__ Al,
    const u16* __restrict__ Bh, const u16* __restrict__ Bl, int K,
    u16* __restrict__ Qh, u16* __restrict__ Ql,
    u16* __restrict__ Kh, u16* __restrict__ Kl,
    u16* __restrict__ VT,
    float* __restrict__ Out, const float* __restrict__ bias) {
  __shared__ u16 As[2][128 * 32];
  __shared__ u16 Bs[2][128 * 32];
  int tid = threadIdx.x;
  int l = tid & 63, w = tid >> 6;
  int lr = l & 15, lg = l >> 4;
  int wr = w >> 1, wc = w & 1;
  int rowA = blockIdx.y * 128, colB = blockIdx.x * 128;
  int r0 = tid >> 2, kk = (tid & 3) * 8;
  const u16* gah = Ah + (size_t)(rowA + r0) * K + kk;
  const u16* gal = Al + (size_t)(rowA + r0) * K + kk;
  const u16* gbh = Bh + (size_t)(colB + r0) * K + kk;
  const u16* gbl = Bl + (size_t)(colB + r0) * K + kk;
  size_t half = (size_t)64 * K;
  f32x4 acc[4][4] = {};
  for (int kb = 0; kb < K; kb += 32) {
    __syncthreads();
    gload16(gah + kb, &As[0][r0 * 32 + kk]);
    gload16(gah + kb + half, &As[0][(64 + r0) * 32 + kk]);
    gload16(gal + kb, &As[1][r0 * 32 + kk]);
    gload16(gal + kb + half, &As[1][(64 + r0) * 32 + kk]);
    gload16(gbh + kb, &Bs[0][r0 * 32 + kk]);
    gload16(gbh + kb + half, &Bs[0][(64 + r0) * 32 + kk]);
    gload16(gbl + kb, &Bs[1][r0 * 32 + kk]);
    gload16(gbl + kb + half, &Bs[1][(64 + r0) * 32 + kk]);
    __syncthreads();
    bf16x8 ah[4], al4[4], bh4[4], bl4[4];
#pragma unroll
    for (int i = 0; i < 4; ++i) {
      ah[i]  = *(const bf16x8*)&As[0][(wr * 64 + i * 16 + lr) * 32 + lg * 8];
      al4[i] = *(const bf16x8*)&As[1][(wr * 64 + i * 16 + lr) * 32 + lg * 8];
      bh4[i] = *(const bf16x8*)&Bs[0][(wc * 64 + i * 16 + lr) * 32 + lg * 8];
      bl4[i] = *(const bf16x8*)&Bs[1][(wc * 64 + i * 16 + lr) * 32 + lg * 8];
    }
#pragma unroll
    for (int i = 0; i < 4; ++i)
#pragma unroll
      for (int j = 0; j < 4; ++j) {
        acc[i][j] = MFMA(ah[i], bh4[j], acc[i][j]);
        acc[i][j] = MFMA(al4[i], bh4[j], acc[i][j]);
        acc[i][j] = MFMA(ah[i], bl4[j], acc[i][j]);
      }
  }
#pragma unroll
  for (int i = 0; i < 4; ++i) {
    int row0 = rowA + wr * 64 + i * 16 + lg * 4;
#pragma unroll
    for (int j = 0; j < 4; ++j) {
      int c = colB + wc * 64 + j * 16 + lr;
      f32x4 v = acc[i][j];
      if (MODE == 0) {
        if (c < 2048) {
#pragma unroll
          for (int r = 0; r < 4; ++r) {
            size_t o = (size_t)(row0 + r) * 2048 + c;
            u16 hh = f2bf(v[r]);
            Qh[o] = hh;
            Ql[o] = f2bf(v[r] - bf2f(hh));
          }
        } else if (c < 2560) {
          int ck = c - 2048;
#pragma unroll
          for (int r = 0; r < 4; ++r) {
            size_t o = (size_t)(row0 + r) * 512 + ck;
            u16 hh = f2bf(v[r]);
            Kh[o] = hh;
            Kl[o] = f2bf(v[r] - bf2f(hh));
          }
        } else {
          int cv = c - 2560, kvh = cv >> 7, d = cv & 127;
          int b = row0 >> 11, t = row0 & 2047;
          union { u16 u[4]; uint2 q; } P;
#pragma unroll
          for (int r = 0; r < 4; ++r) P.u[r] = f2bf(v[r]);
          *(uint2*)&VT[((size_t)(b * 4 + kvh) * 128 + d) * 2048 + t] = P.q;
        }
      } else {
        float bb = bias[c];
#pragma unroll
        for (int r = 0; r < 4; ++r)
          Out[(size_t)(row0 + r) * 2048 + c] = v[r] + bb;
      }
    }
  }
}

// ---------------- flash attention: 16 q-rows per wave, split QK^T ----------------
__global__ __launch_bounds__(256) void attn_kernel(
    const u16* __restrict__ Qh, const u16* __restrict__ Ql,
    const u16* __restrict__ Kh, const u16* __restrict__ Kl,
    const u16* __restrict__ VT,
    u16* __restrict__ Ch, u16* __restrict__ Cl) {
  __shared__ u16 Plds[4][16 * 32];
  int tid = threadIdx.x;
  int w = tid >> 6, l = tid & 63;
  int lr = l & 15, lg = l >> 4;
  int unit = blockIdx.x * 4 + w;
  int qblk = unit >> 6;
  int h = (unit >> 2) & 15;
  int b = unit & 3;
  int q0 = qblk * 16;
  int kvh = h >> 2;

  size_t qbase = (size_t)(b * 2048 + q0 + lr) * 2048 + h * 128 + lg * 8;
  bf16x8 qfh[4], qfl[4];
#pragma unroll
  for (int d = 0; d < 4; ++d) {
    qfh[d] = *(const bf16x8*)(Qh + qbase + d * 32);
    qfl[d] = *(const bf16x8*)(Ql + qbase + d * 32);
  }
  f32x4 o[8] = {};
  float mrun[4] = {-3e38f, -3e38f, -3e38f, -3e38f};
  float lrun[4] = {0.f, 0.f, 0.f, 0.f};

  size_t krow0 = (size_t)(b * 2048) * 512 + (size_t)kvh * 128 + lg * 8;
  size_t vbase = (size_t)((b * 4 + kvh) * 128) * 2048 + lg * 8;
  u16* pl = &Plds[w][0];

  for (int kv0 = 0; kv0 <= q0 + 15; kv0 += 32) {
    f32x4 s[2] = {};
#pragma unroll
    for (int d = 0; d < 4; ++d) {
#pragma unroll
      for (int n = 0; n < 2; ++n) {
        size_t ka = krow0 + (size_t)(kv0 + n * 16 + lr) * 512 + d * 32;
        bf16x8 kfh = *(const bf16x8*)(Kh + ka);
        bf16x8 kfl = *(const bf16x8*)(Kl + ka);
        s[n] = MFMA(qfh[d], kfh, s[n]);
        s[n] = MFMA(qfl[d], kfh, s[n]);
        s[n] = MFMA(qfh[d], kfl, s[n]);
      }
    }
    if (kv0 + 31 > q0) {
#pragma unroll
      for (int n = 0; n < 2; ++n) {
        int kvi = kv0 + n * 16 + lr;
#pragma unroll
        for (int r = 0; r < 4; ++r)
          if (kvi > q0 + lg * 4 + r) s[n][r] = -3e38f;
      }
    }
    float p0[4], p1[4], alpha[4];
#pragma unroll
    for (int r = 0; r < 4; ++r) {
      float t = rmax16(fmaxf(s[0][r], s[1][r]));
      float mn = fmaxf(mrun[r], t);
      alpha[r] = exp2f((mrun[r] - mn) * LOG2E);
      p0[r] = exp2f((s[0][r] - mn) * LOG2E);
      p1[r] = exp2f((s[1][r] - mn) * LOG2E);
      float ps = rsum16(p0[r] + p1[r]);
      lrun[r] = lrun[r] * alpha[r] + ps;
      mrun[r] = mn;
    }
#pragma unroll
    for (int dt = 0; dt < 8; ++dt)
#pragma unroll
      for (int r = 0; r < 4; ++r) o[dt][r] *= alpha[r];
#pragma unroll
    for (int r = 0; r < 4; ++r) {
      pl[(lg * 4 + r) * 32 + lr] = f2bf(p0[r]);
      pl[(lg * 4 + r) * 32 + 16 + lr] = f2bf(p1[r]);
    }
    asm volatile("s_waitcnt lgkmcnt(0)" ::: "memory");
    bf16x8 pf = *(const bf16x8*)&pl[lr * 32 + lg * 8];
#pragma unroll
    for (int dt = 0; dt < 8; ++dt) {
      bf16x8 vf = *(const bf16x8*)(VT + vbase + (size_t)(dt * 16 + lr) * 2048 + kv0);
      o[dt] = MFMA(pf, vf, o[dt]);
    }
  }
#pragma unroll
  for (int dt = 0; dt < 8; ++dt) {
#pragma unroll
    for (int r = 0; r < 4; ++r) {
      float v = o[dt][r] / lrun[r];
      size_t oi = (size_t)(b * 2048 + q0 + lg * 4 + r) * 2048 + h * 128 + dt * 16 + lr;
      u16 hh = f2bf(v);
      Ch[oi] = hh;
      Cl[oi] = f2bf(v - bf2f(hh));
    }
  }
}

extern "C" void kernel_launch(void* const* d_in, const int* in_sizes, int n_in,
                              void* d_out, int out_size, void* d_ws, size_t ws_size,
                              hipStream_t stream) {
  const float* X  = (const float*)d_in[0];
  const float* qw = (const float*)d_in[1];
  const float* kw = (const float*)d_in[2];
  const float* vw = (const float*)d_in[3];
  const float* ow = (const float*)d_in[4];
  const float* ob = (const float*)d_in[5];
  float* Out = (float*)d_out;

  char* ws = (char*)d_ws;
  size_t off = 0;
  auto alloc = [&](size_t bytes) -> void* {
    void* p = ws + off;
    off += (bytes + 255) & ~(size_t)255;
    return p;
  };
  const size_t MK = (size_t)8192 * 2048;  // X / Q / ctx elems
  u16* Xh  = (u16*)alloc(MK * 2);
  u16* Xl  = (u16*)alloc(MK * 2);
  u16* Bth = (u16*)alloc((size_t)3072 * 2048 * 2);
  u16* Btl = (u16*)alloc((size_t)3072 * 2048 * 2);
  u16* OWh = (u16*)alloc((size_t)2048 * 2048 * 2);
  u16* OWl = (u16*)alloc((size_t)2048 * 2048 * 2);
  u16* Qh  = (u16*)alloc(MK * 2);
  u16* Ql  = (u16*)alloc(MK * 2);
  u16* Kh  = (u16*)alloc((size_t)8192 * 512 * 2);
  u16* Kl  = (u16*)alloc((size_t)8192 * 512 * 2);
  u16* VT  = (u16*)alloc((size_t)8192 * 512 * 2);
  u16* Ch  = (u16*)alloc(MK * 2);
  u16* Cl  = (u16*)alloc(MK * 2);

  // 1) split X into bf16 hi/lo
  conv_split<<<dim3(16384), dim3(256), 0, stream>>>((const float4*)X, Xh, Xl,
                                                    (int)(MK / 4));
  // 2) transpose+split weights: Bt rows [0,2048)=q_w^T, [2048,2560)=k_w^T, [2560,3072)=v_w^T
  dim3 tb(32, 8);
  transpose_split<<<dim3(64, 64), tb, 0, stream>>>(qw, 2048, 2048, Bth, Btl, 0);
  transpose_split<<<dim3(16, 64), tb, 0, stream>>>(kw, 2048, 512, Bth, Btl, 2048);
  transpose_split<<<dim3(16, 64), tb, 0, stream>>>(vw, 2048, 512, Bth, Btl, 2560);
  transpose_split<<<dim3(64, 64), tb, 0, stream>>>(ow, 2048, 2048, OWh, OWl, 0);
  // 3) fused QKV projection
  gemm_split<0><<<dim3(24, 64), dim3(256), 0, stream>>>(
      Xh, Xl, Bth, Btl, 2048, Qh, Ql, Kh, Kl, VT, nullptr, nullptr);
  // 4) flash attention
  attn_kernel<<<dim3(2048), dim3(256), 0, stream>>>(Qh, Ql, Kh, Kl, VT, Ch, Cl);
  // 5) out projection + bias
  gemm_split<1><<<dim3(16, 64), dim3(256), 0, stream>>>(
      Ch, Cl, OWh, OWl, 2048, nullptr, nullptr, nullptr, nullptr, nullptr, Out, ob);
}

// Round 2
// 1060.089 us; speedup vs baseline: 1.2730x; 1.2730x over previous
//
#include <hip/hip_runtime.h>

typedef unsigned short u16;
typedef unsigned int   u32;
typedef __attribute__((ext_vector_type(8))) __bf16 bf16x8;
typedef __attribute__((ext_vector_type(4))) float  f32x4;

#define LOG2E 1.44269504088896340f

__device__ __forceinline__ u16 f2bf(float x) {
  u32 u = __float_as_uint(x);
  u32 r = u + 0x7fffu + ((u >> 16) & 1u);
  return (u16)(r >> 16);
}
__device__ __forceinline__ float bf2f(u16 h) {
  return __uint_as_float(((u32)h) << 16);
}
__device__ __forceinline__ void gload16(const u16* g, u16* l) {
  __builtin_amdgcn_global_load_lds(
      (const __attribute__((address_space(1))) void*)g,
      (__attribute__((address_space(3))) void*)l, 16, 0, 0);
}
__device__ __forceinline__ f32x4 MFMA(bf16x8 a, bf16x8 b, f32x4 c) {
  return __builtin_amdgcn_mfma_f32_16x16x32_bf16(a, b, c, 0, 0, 0);
}
__device__ __forceinline__ float rmax16(float x) {
  x = fmaxf(x, __shfl_xor(x, 1));
  x = fmaxf(x, __shfl_xor(x, 2));
  x = fmaxf(x, __shfl_xor(x, 4));
  x = fmaxf(x, __shfl_xor(x, 8));
  return x;
}
__device__ __forceinline__ float rsum16(float x) {
  x += __shfl_xor(x, 1);
  x += __shfl_xor(x, 2);
  x += __shfl_xor(x, 4);
  x += __shfl_xor(x, 8);
  return x;
}

// ---------------- elementwise fp32 -> bf16 hi/lo split ----------------
__global__ void conv_split(const float4* __restrict__ src,
                           u16* __restrict__ dh, u16* __restrict__ dl, int n4) {
  int i = blockIdx.x * 256 + threadIdx.x;
  if (i >= n4) return;
  float4 v = src[i];
  float a[4] = {v.x, v.y, v.z, v.w};
  union { u16 u[4]; uint2 q; } H, L;
#pragma unroll
  for (int k = 0; k < 4; ++k) {
    u16 hh = f2bf(a[k]);
    H.u[k] = hh;
    L.u[k] = f2bf(a[k] - bf2f(hh));
  }
  *(uint2*)&dh[(size_t)i * 4] = H.q;
  *(uint2*)&dl[(size_t)i * 4] = L.q;
}

// ---------------- transpose [K x N] fp32 -> [N x 2048] bf16 hi/lo ----------------
__global__ void transpose_split(const float* __restrict__ src, int K, int N,
                                u16* __restrict__ dh, u16* __restrict__ dl,
                                int rowOff) {
  __shared__ float t[32][33];
  int n0 = blockIdx.x * 32, k0 = blockIdx.y * 32;
  int tx = threadIdx.x, ty = threadIdx.y;
#pragma unroll
  for (int i = 0; i < 4; ++i)
    t[ty + 8 * i][tx] = src[(size_t)(k0 + ty + 8 * i) * N + n0 + tx];
  __syncthreads();
#pragma unroll
  for (int i = 0; i < 4; ++i) {
    int n = n0 + ty + 8 * i, k = k0 + tx;
    float v = t[tx][ty + 8 * i];
    u16 hh = f2bf(v);
    size_t o = (size_t)(rowOff + n) * 2048 + k;
    dh[o] = hh;
    dl[o] = f2bf(v - bf2f(hh));
  }
}

// ---------------- split-bf16 GEMM: C = A(hi+lo) * B(hi+lo)^T ----------------
template <int MODE>
__global__ __launch_bounds__(256) void gemm_split(
    const u16* __restrict__ Ah, const u16* __restrict__ Al,
    const u16* __restrict__ Bh, const u16* __restrict__ Bl, int K,
    u16* __restrict__ Qh, u16* __restrict__ Ql,
    u16* __restrict__ Kh, u16* __restrict__ Kl,
    u16* __restrict__ VT,
    float* __restrict__ Out, const float* __restrict__ bias) {
  __shared__ u16 As[2][128 * 32];
  __shared__ u16 Bs[2][128 * 32];
  int tid = threadIdx.x;
  int l = tid & 63, w = tid >> 6;
  int lr = l & 15, lg = l >> 4;
  int wr = w >> 1, wc = w & 1;
  int rowA = blockIdx.y * 128, colB = blockIdx.x * 128;
  int r0 = tid >> 2, kk = (tid & 3) * 8;
  const u16* gah = Ah + (size_t)(rowA + r0) * K + kk;
  const u16* gal = Al + (size_t)(rowA + r0) * K + kk;
  const u16* gbh = Bh + (size_t)(colB + r0) * K + kk;
  const u16* gbl = Bl + (size_t)(colB + r0) * K + kk;
  size_t half = (size_t)64 * K;
  f32x4 acc[4][4] = {};
  for (int kb = 0; kb < K; kb += 32) {
    __syncthreads();
    gload16(gah + kb, &As[0][r0 * 32 + kk]);
    gload16(gah + kb + half, &As[0][(64 + r0) * 32 + kk]);
    gload16(gal + kb, &As[1][r0 * 32 + kk]);
    gload16(gal + kb + half, &As[1][(64 + r0) * 32 + kk]);
    gload16(gbh + kb, &Bs[0][r0 * 32 + kk]);
    gload16(gbh + kb + half, &Bs[0][(64 + r0) * 32 + kk]);
    gload16(gbl + kb, &Bs[1][r0 * 32 + kk]);
    gload16(gbl + kb + half, &Bs[1][(64 + r0) * 32 + kk]);
    __syncthreads();
    bf16x8 ah[4], al4[4], bh4[4], bl4[4];
#pragma unroll
    for (int i = 0; i < 4; ++i) {
      ah[i]  = *(const bf16x8*)&As[0][(wr * 64 + i * 16 + lr) * 32 + lg * 8];
      al4[i] = *(const bf16x8*)&As[1][(wr * 64 + i * 16 + lr) * 32 + lg * 8];
      bh4[i] = *(const bf16x8*)&Bs[0][(wc * 64 + i * 16 + lr) * 32 + lg * 8];
      bl4[i] = *(const bf16x8*)&Bs[1][(wc * 64 + i * 16 + lr) * 32 + lg * 8];
    }
#pragma unroll
    for (int i = 0; i < 4; ++i)
#pragma unroll
      for (int j = 0; j < 4; ++j) {
        acc[i][j] = MFMA(ah[i], bh4[j], acc[i][j]);
        acc[i][j] = MFMA(al4[i], bh4[j], acc[i][j]);
        acc[i][j] = MFMA(ah[i], bl4[j], acc[i][j]);
      }
  }
#pragma unroll
  for (int i = 0; i < 4; ++i) {
    int row0 = rowA + wr * 64 + i * 16 + lg * 4;
#pragma unroll
    for (int j = 0; j < 4; ++j) {
      int c = colB + wc * 64 + j * 16 + lr;
      f32x4 v = acc[i][j];
      if (MODE == 0) {
        if (c < 2048) {
#pragma unroll
          for (int r = 0; r < 4; ++r) {
            size_t o = (size_t)(row0 + r) * 2048 + c;
            u16 hh = f2bf(v[r]);
            Qh[o] = hh;
            Ql[o] = f2bf(v[r] - bf2f(hh));
          }
        } else if (c < 2560) {
          int ck = c - 2048;
#pragma unroll
          for (int r = 0; r < 4; ++r) {
            size_t o = (size_t)(row0 + r) * 512 + ck;
            u16 hh = f2bf(v[r]);
            Kh[o] = hh;
            Kl[o] = f2bf(v[r] - bf2f(hh));
          }
        } else {
          int cv = c - 2560, kvh = cv >> 7, d = cv & 127;
          int b = row0 >> 11, t = row0 & 2047;
          union { u16 u[4]; uint2 q; } P;
#pragma unroll
          for (int r = 0; r < 4; ++r) P.u[r] = f2bf(v[r]);
          *(uint2*)&VT[((size_t)(b * 4 + kvh) * 128 + d) * 2048 + t] = P.q;
        }
      } else {
        float bb = bias[c];
#pragma unroll
        for (int r = 0; r < 4; ++r)
          Out[(size_t)(row0 + r) * 2048 + c] = v[r] + bb;
      }
    }
  }
}

// ---------------- flash attention v2: 128-q-rows/block, LDS-staged K/V ----------------
// 8 waves x 16 q-rows; KV-step 64; Kh/Kl/V staged via global_load_lds with
// XOR-swizzled source (linear dest), conflict-free ds_read_b128 on read side.
__global__ __launch_bounds__(512) void attn_kernel(
    const u16* __restrict__ Qh, const u16* __restrict__ Ql,
    const u16* __restrict__ Kh, const u16* __restrict__ Kl,
    const u16* __restrict__ VT,
    u16* __restrict__ Ch, u16* __restrict__ Cl) {
  __shared__ u16 Ksh[64 * 128];   // [kv 64][d 128], slot16B ^= (row&7)
  __shared__ u16 Ksl[64 * 128];
  __shared__ u16 Vs[128 * 64];    // [d 128][kv 64], slot16B ^= (d&7)
  __shared__ u16 Ps[8][16 * 64];  // per-wave P [q 16][kv 64], slot16B ^= (q&7)

  int tid = threadIdx.x;
  int w = tid >> 6, l = tid & 63;
  int lr = l & 15, lg = l >> 4;

  int bid = blockIdx.x;
  int qblk = bid & 15;
  int hg = (bid >> 4) & 3;
  int kvh = (bid >> 6) & 3;
  int b = bid >> 8;
  int h = kvh * 4 + hg;
  int q0 = qblk * 128;
  int qr0 = q0 + w * 16;  // this wave's first q row

  // Q fragments in registers (hi+lo)
  size_t qbase = (size_t)(b * 2048 + qr0 + lr) * 2048 + h * 128 + lg * 8;
  bf16x8 qfh[4], qfl[4];
#pragma unroll
  for (int d = 0; d < 4; ++d) {
    qfh[d] = *(const bf16x8*)(Qh + qbase + d * 32);
    qfl[d] = *(const bf16x8*)(Ql + qbase + d * 32);
  }

  f32x4 o[8] = {};
  float mrun[4] = {-3e38f, -3e38f, -3e38f, -3e38f};
  float lrun[4] = {0.f, 0.f, 0.f, 0.f};

  const u16* Kbh = Kh + (size_t)(b * 2048) * 512 + kvh * 128;
  const u16* Kbl = Kl + (size_t)(b * 2048) * 512 + kvh * 128;
  const u16* Vb  = VT + (size_t)((b * 4 + kvh) * 128) * 2048;
  u16* pw = &Ps[w][0];

  int kvEnd = q0 + 128;
  for (int kv0 = 0; kv0 < kvEnd; kv0 += 64) {
    __syncthreads();
    // ---- stage Kh/Kl (64x128, 16KB each) + V (128x64, 16KB), swizzled source
#pragma unroll
    for (int p = 0; p < 2; ++p) {
      int o16 = p * 512 + tid;
      int krow = o16 >> 4;
      int kslot = ((o16 & 15) ^ (krow & 7)) * 8;
      size_t ksrc = (size_t)(kv0 + krow) * 512 + kslot;
      gload16(Kbh + ksrc, &Ksh[o16 * 8]);
      gload16(Kbl + ksrc, &Ksl[o16 * 8]);
      int vrow = o16 >> 3;
      int vslot = ((o16 & 7) ^ (vrow & 7)) * 8;
      gload16(Vb + (size_t)vrow * 2048 + kv0 + vslot, &Vs[o16 * 8]);
    }
    __syncthreads();
    if (kv0 > qr0 + 15) continue;  // wave-uniform: fully masked step

    // ---- QK^T (split, 3 MFMA) over 4 kv sub-tiles
    f32x4 s[4] = {};
#pragma unroll
    for (int d = 0; d < 4; ++d) {
#pragma unroll
      for (int n = 0; n < 4; ++n) {
        int row = n * 16 + lr;
        int sl = ((d * 4 + lg) ^ (row & 7)) * 8;
        bf16x8 kfh = *(const bf16x8*)&Ksh[row * 128 + sl];
        bf16x8 kfl = *(const bf16x8*)&Ksl[row * 128 + sl];
        s[n] = MFMA(qfh[d], kfh, s[n]);
        s[n] = MFMA(qfl[d], kfh, s[n]);
        s[n] = MFMA(qfh[d], kfl, s[n]);
      }
    }
    // ---- causal mask (diagonal steps only)
    if (kv0 + 63 > qr0) {
#pragma unroll
      for (int n = 0; n < 4; ++n) {
        int kvi = kv0 + n * 16 + lr;
#pragma unroll
        for (int r = 0; r < 4; ++r)
          if (kvi > qr0 + lg * 4 + r) s[n][r] = -3e38f;
      }
    }
    // ---- online softmax
    float alpha[4];
    float pv[4][4];
#pragma unroll
    for (int r = 0; r < 4; ++r) {
      float t = fmaxf(fmaxf(s[0][r], s[1][r]), fmaxf(s[2][r], s[3][r]));
      t = rmax16(t);
      float mn = fmaxf(mrun[r], t);
      alpha[r] = exp2f((mrun[r] - mn) * LOG2E);
      float ps = 0.f;
#pragma unroll
      for (int n = 0; n < 4; ++n) {
        pv[n][r] = exp2f((s[n][r] - mn) * LOG2E);
        ps += pv[n][r];
      }
      ps = rsum16(ps);
      lrun[r] = lrun[r] * alpha[r] + ps;
      mrun[r] = mn;
    }
#pragma unroll
    for (int dt = 0; dt < 8; ++dt)
#pragma unroll
      for (int r = 0; r < 4; ++r) o[dt][r] *= alpha[r];
    // ---- P -> LDS (swizzled), then PV
#pragma unroll
    for (int n = 0; n < 4; ++n) {
      int colhi = n * 2 + (lr >> 3);
#pragma unroll
      for (int r = 0; r < 4; ++r) {
        int row = lg * 4 + r;
        pw[row * 64 + ((colhi ^ (row & 7)) * 8) + (lr & 7)] = f2bf(pv[n][r]);
      }
    }
    asm volatile("s_waitcnt lgkmcnt(0)" ::: "memory");
#pragma unroll
    for (int n2 = 0; n2 < 2; ++n2) {
      bf16x8 pf = *(const bf16x8*)&pw[lr * 64 + (((n2 * 4 + lg) ^ (lr & 7)) * 8)];
#pragma unroll
      for (int dt = 0; dt < 8; ++dt) {
        int d = dt * 16 + lr;
        bf16x8 vf = *(const bf16x8*)&Vs[d * 64 + (((n2 * 4 + lg) ^ (lr & 7)) * 8)];
        o[dt] = MFMA(pf, vf, o[dt]);
      }
    }
  }
  // ---- epilogue: normalize, split-write context
#pragma unroll
  for (int dt = 0; dt < 8; ++dt) {
#pragma unroll
    for (int r = 0; r < 4; ++r) {
      float v = o[dt][r] / lrun[r];
      size_t oi = (size_t)(b * 2048 + qr0 + lg * 4 + r) * 2048 + h * 128 + dt * 16 + lr;
      u16 hh = f2bf(v);
      Ch[oi] = hh;
      Cl[oi] = f2bf(v - bf2f(hh));
    }
  }
}

extern "C" void kernel_launch(void* const* d_in, const int* in_sizes, int n_in,
                              void* d_out, int out_size, void* d_ws, size_t ws_size,
                              hipStream_t stream) {
  const float* X  = (const float*)d_in[0];
  const float* qw = (const float*)d_in[1];
  const float* kw = (const float*)d_in[2];
  const float* vw = (const float*)d_in[3];
  const float* ow = (const float*)d_in[4];
  const float* ob = (const float*)d_in[5];
  float* Out = (float*)d_out;

  char* ws = (char*)d_ws;
  size_t off = 0;
  auto alloc = [&](size_t bytes) -> void* {
    void* p = ws + off;
    off += (bytes + 255) & ~(size_t)255;
    return p;
  };
  const size_t MK = (size_t)8192 * 2048;
  u16* Xh  = (u16*)alloc(MK * 2);
  u16* Xl  = (u16*)alloc(MK * 2);
  u16* Bth = (u16*)alloc((size_t)3072 * 2048 * 2);
  u16* Btl = (u16*)alloc((size_t)3072 * 2048 * 2);
  u16* OWh = (u16*)alloc((size_t)2048 * 2048 * 2);
  u16* OWl = (u16*)alloc((size_t)2048 * 2048 * 2);
  u16* Qh  = (u16*)alloc(MK * 2);
  u16* Ql  = (u16*)alloc(MK * 2);
  u16* Kh  = (u16*)alloc((size_t)8192 * 512 * 2);
  u16* Kl  = (u16*)alloc((size_t)8192 * 512 * 2);
  u16* VT  = (u16*)alloc((size_t)8192 * 512 * 2);
  u16* Ch  = (u16*)alloc(MK * 2);
  u16* Cl  = (u16*)alloc(MK * 2);

  conv_split<<<dim3(16384), dim3(256), 0, stream>>>((const float4*)X, Xh, Xl,
                                                    (int)(MK / 4));
  dim3 tb(32, 8);
  transpose_split<<<dim3(64, 64), tb, 0, stream>>>(qw, 2048, 2048, Bth, Btl, 0);
  transpose_split<<<dim3(16, 64), tb, 0, stream>>>(kw, 2048, 512, Bth, Btl, 2048);
  transpose_split<<<dim3(16, 64), tb, 0, stream>>>(vw, 2048, 512, Bth, Btl, 2560);
  transpose_split<<<dim3(64, 64), tb, 0, stream>>>(ow, 2048, 2048, OWh, OWl, 0);
  gemm_split<0><<<dim3(24, 64), dim3(256), 0, stream>>>(
      Xh, Xl, Bth, Btl, 2048, Qh, Ql, Kh, Kl, VT, nullptr, nullptr);
  attn_kernel<<<dim3(1024), dim3(512), 0, stream>>>(Qh, Ql, Kh, Kl, VT, Ch, Cl);
  gemm_split<1><<<dim3(16, 64), dim3(256), 0, stream>>>(
      Ch, Cl, OWh, OWl, 2048, nullptr, nullptr, nullptr, nullptr, nullptr, Out, ob);
}

// Round 3
// 796.009 us; speedup vs baseline: 1.6953x; 1.3318x over previous
//
#include <hip/hip_runtime.h>

typedef unsigned short u16;
typedef unsigned int   u32;
typedef __attribute__((ext_vector_type(8))) __bf16 bf16x8;
typedef __attribute__((ext_vector_type(4))) float  f32x4;

#define LOG2E 1.44269504088896340f

__device__ __forceinline__ u16 f2bf(float x) {
  u32 u = __float_as_uint(x);
  u32 r = u + 0x7fffu + ((u >> 16) & 1u);
  return (u16)(r >> 16);
}
__device__ __forceinline__ float bf2f(u16 h) {
  return __uint_as_float(((u32)h) << 16);
}
__device__ __forceinline__ void gload16(const u16* g, u16* l) {
  __builtin_amdgcn_global_load_lds(
      (const __attribute__((address_space(1))) void*)g,
      (__attribute__((address_space(3))) void*)l, 16, 0, 0);
}
__device__ __forceinline__ f32x4 MFMA(bf16x8 a, bf16x8 b, f32x4 c) {
  return __builtin_amdgcn_mfma_f32_16x16x32_bf16(a, b, c, 0, 0, 0);
}
__device__ __forceinline__ float rmax16(float x) {
  x = fmaxf(x, __shfl_xor(x, 1));
  x = fmaxf(x, __shfl_xor(x, 2));
  x = fmaxf(x, __shfl_xor(x, 4));
  x = fmaxf(x, __shfl_xor(x, 8));
  return x;
}
__device__ __forceinline__ float rsum16(float x) {
  x += __shfl_xor(x, 1);
  x += __shfl_xor(x, 2);
  x += __shfl_xor(x, 4);
  x += __shfl_xor(x, 8);
  return x;
}

// ---------------- elementwise fp32 -> bf16 hi/lo split ----------------
__global__ void conv_split(const float4* __restrict__ src,
                           u16* __restrict__ dh, u16* __restrict__ dl, int n4) {
  int i = blockIdx.x * 256 + threadIdx.x;
  if (i >= n4) return;
  float4 v = src[i];
  float a[4] = {v.x, v.y, v.z, v.w};
  union { u16 u[4]; uint2 q; } H, L;
#pragma unroll
  for (int k = 0; k < 4; ++k) {
    u16 hh = f2bf(a[k]);
    H.u[k] = hh;
    L.u[k] = f2bf(a[k] - bf2f(hh));
  }
  *(uint2*)&dh[(size_t)i * 4] = H.q;
  *(uint2*)&dl[(size_t)i * 4] = L.q;
}

// ---------------- transpose [K x N] fp32 -> [N x 2048] bf16 hi/lo ----------------
__global__ void transpose_split(const float* __restrict__ src, int K, int N,
                                u16* __restrict__ dh, u16* __restrict__ dl,
                                int rowOff) {
  __shared__ float t[32][33];
  int n0 = blockIdx.x * 32, k0 = blockIdx.y * 32;
  int tx = threadIdx.x, ty = threadIdx.y;
#pragma unroll
  for (int i = 0; i < 4; ++i)
    t[ty + 8 * i][tx] = src[(size_t)(k0 + ty + 8 * i) * N + n0 + tx];
  __syncthreads();
#pragma unroll
  for (int i = 0; i < 4; ++i) {
    int n = n0 + ty + 8 * i, k = k0 + tx;
    float v = t[tx][ty + 8 * i];
    u16 hh = f2bf(v);
    size_t o = (size_t)(rowOff + n) * 2048 + k;
    dh[o] = hh;
    dl[o] = f2bf(v - bf2f(hh));
  }
}

// ---------------- split-bf16 GEMM: C = A(hi+lo) * B(hi+lo)^T ----------------
template <int MODE>
__global__ __launch_bounds__(256) void gemm_split(
    const u16* __restrict__ Ah, const u16* __restrict__ Al,
    const u16* __restrict__ Bh, const u16* __restrict__ Bl, int K,
    u16* __restrict__ Qh, u16* __restrict__ Ql,
    u16* __restrict__ Kh, u16* __restrict__ Kl,
    u16* __restrict__ VT,
    float* __restrict__ Out, const float* __restrict__ bias) {
  __shared__ u16 As[2][128 * 32];
  __shared__ u16 Bs[2][128 * 32];
  int tid = threadIdx.x;
  int l = tid & 63, w = tid >> 6;
  int lr = l & 15, lg = l >> 4;
  int wr = w >> 1, wc = w & 1;
  int rowA = blockIdx.y * 128, colB = blockIdx.x * 128;
  int r0 = tid >> 2, kk = (tid & 3) * 8;
  const u16* gah = Ah + (size_t)(rowA + r0) * K + kk;
  const u16* gal = Al + (size_t)(rowA + r0) * K + kk;
  const u16* gbh = Bh + (size_t)(colB + r0) * K + kk;
  const u16* gbl = Bl + (size_t)(colB + r0) * K + kk;
  size_t half = (size_t)64 * K;
  f32x4 acc[4][4] = {};
  for (int kb = 0; kb < K; kb += 32) {
    __syncthreads();
    gload16(gah + kb, &As[0][r0 * 32 + kk]);
    gload16(gah + kb + half, &As[0][(64 + r0) * 32 + kk]);
    gload16(gal + kb, &As[1][r0 * 32 + kk]);
    gload16(gal + kb + half, &As[1][(64 + r0) * 32 + kk]);
    gload16(gbh + kb, &Bs[0][r0 * 32 + kk]);
    gload16(gbh + kb + half, &Bs[0][(64 + r0) * 32 + kk]);
    gload16(gbl + kb, &Bs[1][r0 * 32 + kk]);
    gload16(gbl + kb + half, &Bs[1][(64 + r0) * 32 + kk]);
    __syncthreads();
    bf16x8 ah[4], al4[4], bh4[4], bl4[4];
#pragma unroll
    for (int i = 0; i < 4; ++i) {
      ah[i]  = *(const bf16x8*)&As[0][(wr * 64 + i * 16 + lr) * 32 + lg * 8];
      al4[i] = *(const bf16x8*)&As[1][(wr * 64 + i * 16 + lr) * 32 + lg * 8];
      bh4[i] = *(const bf16x8*)&Bs[0][(wc * 64 + i * 16 + lr) * 32 + lg * 8];
      bl4[i] = *(const bf16x8*)&Bs[1][(wc * 64 + i * 16 + lr) * 32 + lg * 8];
    }
#pragma unroll
    for (int i = 0; i < 4; ++i)
#pragma unroll
      for (int j = 0; j < 4; ++j) {
        acc[i][j] = MFMA(ah[i], bh4[j], acc[i][j]);
        acc[i][j] = MFMA(al4[i], bh4[j], acc[i][j]);
        acc[i][j] = MFMA(ah[i], bl4[j], acc[i][j]);
      }
  }
#pragma unroll
  for (int i = 0; i < 4; ++i) {
    int row0 = rowA + wr * 64 + i * 16 + lg * 4;
#pragma unroll
    for (int j = 0; j < 4; ++j) {
      int c = colB + wc * 64 + j * 16 + lr;
      f32x4 v = acc[i][j];
      if (MODE == 0) {
        if (c < 2048) {
#pragma unroll
          for (int r = 0; r < 4; ++r) {
            size_t o = (size_t)(row0 + r) * 2048 + c;
            u16 hh = f2bf(v[r]);
            Qh[o] = hh;
            Ql[o] = f2bf(v[r] - bf2f(hh));
          }
        } else if (c < 2560) {
          int ck = c - 2048;
#pragma unroll
          for (int r = 0; r < 4; ++r) {
            size_t o = (size_t)(row0 + r) * 512 + ck;
            u16 hh = f2bf(v[r]);
            Kh[o] = hh;
            Kl[o] = f2bf(v[r] - bf2f(hh));
          }
        } else {
          int cv = c - 2560, kvh = cv >> 7, d = cv & 127;
          int b = row0 >> 11, t = row0 & 2047;
          union { u16 u[4]; uint2 q; } P;
#pragma unroll
          for (int r = 0; r < 4; ++r) P.u[r] = f2bf(v[r]);
          *(uint2*)&VT[((size_t)(b * 4 + kvh) * 128 + d) * 2048 + t] = P.q;
        }
      } else {
        float bb = bias[c];
#pragma unroll
        for (int r = 0; r < 4; ++r)
          Out[(size_t)(row0 + r) * 2048 + c] = v[r] + bb;
      }
    }
  }
}

// ---------------- flash attention v3 ----------------
// 512 blocks, each: two q-tiles (15-p, p) -> uniform 34 kv-steps/block.
// Double-buffered K/V staging (stage t+1 || compute t), raw barriers,
// vmcnt(0) drained once per step AFTER compute. Defer-rescale softmax.
__global__ __launch_bounds__(512) void attn_kernel(
    const u16* __restrict__ Qh, const u16* __restrict__ Ql,
    const u16* __restrict__ Kh, const u16* __restrict__ Kl,
    const u16* __restrict__ VT,
    u16* __restrict__ Ch, u16* __restrict__ Cl) {
  __shared__ u16 Ksh[2][64 * 128];   // [kv 64][d 128], slot16B ^= (row&7)
  __shared__ u16 Ksl[2][64 * 128];
  __shared__ u16 Vs[2][128 * 64];    // [d 128][kv 64], slot16B ^= (d&7)
  __shared__ u16 Ps[8][16 * 64];     // per-wave P, slot16B ^= (q&7)

  int tid = threadIdx.x;
  int w = tid >> 6, l = tid & 63;
  int lr = l & 15, lg = l >> 4;

  int bid = blockIdx.x;
  int pair = bid & 7;
  int hg = (bid >> 3) & 3;
  int kvh = (bid >> 5) & 3;
  int b = bid >> 7;
  int h = kvh * 4 + hg;

  const u16* Kbh = Kh + (size_t)(b * 2048) * 512 + kvh * 128;
  const u16* Kbl = Kl + (size_t)(b * 2048) * 512 + kvh * 128;
  const u16* Vb  = VT + (size_t)((b * 4 + kvh) * 128) * 2048;
  u16* pw = &Ps[w][0];

  auto STAGE = [&](int t, int bufi) {
    int kv0 = t * 64;
#pragma unroll
    for (int p = 0; p < 2; ++p) {
      int o16 = p * 512 + tid;
      int krow = o16 >> 4;
      int kslot = ((o16 & 15) ^ (krow & 7)) * 8;
      size_t ksrc = (size_t)(kv0 + krow) * 512 + kslot;
      gload16(Kbh + ksrc, &Ksh[bufi][o16 * 8]);
      gload16(Kbl + ksrc, &Ksl[bufi][o16 * 8]);
      int vrow = o16 >> 3;
      int vslot = ((o16 & 7) ^ (vrow & 7)) * 8;
      gload16(Vb + (size_t)vrow * 2048 + kv0 + vslot, &Vs[bufi][o16 * 8]);
    }
  };

  for (int pass = 0; pass < 2; ++pass) {
    int tIdx = pass == 0 ? (15 - pair) : pair;
    int q0 = tIdx * 128;
    int qr0 = q0 + w * 16;
    int nt = q0 / 64 + 2;

    // Q fragments in registers (hi+lo)
    size_t qbase = (size_t)(b * 2048 + qr0 + lr) * 2048 + h * 128 + lg * 8;
    bf16x8 qfh[4], qfl[4];
#pragma unroll
    for (int d = 0; d < 4; ++d) {
      qfh[d] = *(const bf16x8*)(Qh + qbase + d * 32);
      qfl[d] = *(const bf16x8*)(Ql + qbase + d * 32);
    }

    f32x4 o[8] = {};
    float mrun[4] = {-3e38f, -3e38f, -3e38f, -3e38f};
    float lrun[4] = {0.f, 0.f, 0.f, 0.f};

    // prologue: stage tile 0
    STAGE(0, 0);
    asm volatile("s_waitcnt vmcnt(0)" ::: "memory");
    __builtin_amdgcn_sched_barrier(0);
    __builtin_amdgcn_s_barrier();
    __builtin_amdgcn_sched_barrier(0);

    int cur = 0;
    for (int t = 0; t < nt; ++t) {
      int kv0 = t * 64;
      if (t + 1 < nt) STAGE(t + 1, cur ^ 1);

      if (kv0 <= qr0 + 15) {
        // ---- QK^T (split, 3 MFMA)
        f32x4 s[4] = {};
        __builtin_amdgcn_s_setprio(1);
#pragma unroll
        for (int d = 0; d < 4; ++d) {
#pragma unroll
          for (int n = 0; n < 4; ++n) {
            int row = n * 16 + lr;
            int sl = ((d * 4 + lg) ^ (row & 7)) * 8;
            bf16x8 kfh = *(const bf16x8*)&Ksh[cur][row * 128 + sl];
            bf16x8 kfl = *(const bf16x8*)&Ksl[cur][row * 128 + sl];
            s[n] = MFMA(qfh[d], kfh, s[n]);
            s[n] = MFMA(qfl[d], kfh, s[n]);
            s[n] = MFMA(qfh[d], kfl, s[n]);
          }
        }
        __builtin_amdgcn_s_setprio(0);
        // ---- causal mask (diagonal steps only)
        if (kv0 + 63 > qr0) {
#pragma unroll
          for (int n = 0; n < 4; ++n) {
            int kvi = kv0 + n * 16 + lr;
#pragma unroll
            for (int r = 0; r < 4; ++r)
              if (kvi > qr0 + lg * 4 + r) s[n][r] = -3e38f;
          }
        }
        // ---- online softmax with defer-rescale
        float tm[4];
#pragma unroll
        for (int r = 0; r < 4; ++r)
          tm[r] = rmax16(fmaxf(fmaxf(s[0][r], s[1][r]), fmaxf(s[2][r], s[3][r])));
        bool grow = (tm[0] > mrun[0]) || (tm[1] > mrun[1]) ||
                    (tm[2] > mrun[2]) || (tm[3] > mrun[3]);
        if (__any(grow)) {
          float alpha[4];
#pragma unroll
          for (int r = 0; r < 4; ++r) {
            float mn = fmaxf(mrun[r], tm[r]);
            alpha[r] = __builtin_amdgcn_exp2f((mrun[r] - mn) * LOG2E);
            mrun[r] = mn;
            lrun[r] *= alpha[r];
          }
#pragma unroll
          for (int dt = 0; dt < 8; ++dt)
#pragma unroll
            for (int r = 0; r < 4; ++r) o[dt][r] *= alpha[r];
        }
        float pv[4][4];
#pragma unroll
        for (int r = 0; r < 4; ++r) {
          float mL = mrun[r] * LOG2E;
          float ps = 0.f;
#pragma unroll
          for (int n = 0; n < 4; ++n) {
            pv[n][r] = __builtin_amdgcn_exp2f(fmaf(s[n][r], LOG2E, -mL));
            ps += pv[n][r];
          }
          lrun[r] += rsum16(ps);
        }
        // ---- P -> LDS (swizzled), then PV
#pragma unroll
        for (int n = 0; n < 4; ++n) {
          int colhi = n * 2 + (lr >> 3);
#pragma unroll
          for (int r = 0; r < 4; ++r) {
            int row = lg * 4 + r;
            pw[row * 64 + ((colhi ^ (row & 7)) * 8) + (lr & 7)] = f2bf(pv[n][r]);
          }
        }
        asm volatile("s_waitcnt lgkmcnt(0)" ::: "memory");
        __builtin_amdgcn_sched_barrier(0);
        __builtin_amdgcn_s_setprio(1);
#pragma unroll
        for (int n2 = 0; n2 < 2; ++n2) {
          bf16x8 pf = *(const bf16x8*)&pw[lr * 64 + (((n2 * 4 + lg) ^ (lr & 7)) * 8)];
#pragma unroll
          for (int dt = 0; dt < 8; ++dt) {
            int d = dt * 16 + lr;
            bf16x8 vf = *(const bf16x8*)&Vs[cur][d * 64 + (((n2 * 4 + lg) ^ (lr & 7)) * 8)];
            o[dt] = MFMA(pf, vf, o[dt]);
          }
        }
        __builtin_amdgcn_s_setprio(0);
      }
      // ---- end-of-step: drain next-tile staging + all LDS, barrier, swap
      asm volatile("s_waitcnt vmcnt(0) lgkmcnt(0)" ::: "memory");
      __builtin_amdgcn_sched_barrier(0);
      __builtin_amdgcn_s_barrier();
      __builtin_amdgcn_sched_barrier(0);
      cur ^= 1;
    }
    // ---- epilogue: normalize, split-write context
#pragma unroll
    for (int dt = 0; dt < 8; ++dt) {
#pragma unroll
      for (int r = 0; r < 4; ++r) {
        float v = o[dt][r] / lrun[r];
        size_t oi = (size_t)(b * 2048 + qr0 + lg * 4 + r) * 2048 + h * 128 + dt * 16 + lr;
        u16 hh = f2bf(v);
        Ch[oi] = hh;
        Cl[oi] = f2bf(v - bf2f(hh));
      }
    }
  }
}

extern "C" void kernel_launch(void* const* d_in, const int* in_sizes, int n_in,
                              void* d_out, int out_size, void* d_ws, size_t ws_size,
                              hipStream_t stream) {
  const float* X  = (const float*)d_in[0];
  const float* qw = (const float*)d_in[1];
  const float* kw = (const float*)d_in[2];
  const float* vw = (const float*)d_in[3];
  const float* ow = (const float*)d_in[4];
  const float* ob = (const float*)d_in[5];
  float* Out = (float*)d_out;

  char* ws = (char*)d_ws;
  size_t off = 0;
  auto alloc = [&](size_t bytes) -> void* {
    void* p = ws + off;
    off += (bytes + 255) & ~(size_t)255;
    return p;
  };
  const size_t MK = (size_t)8192 * 2048;
  u16* Xh  = (u16*)alloc(MK * 2);
  u16* Xl  = (u16*)alloc(MK * 2);
  u16* Bth = (u16*)alloc((size_t)3072 * 2048 * 2);
  u16* Btl = (u16*)alloc((size_t)3072 * 2048 * 2);
  u16* OWh = (u16*)alloc((size_t)2048 * 2048 * 2);
  u16* OWl = (u16*)alloc((size_t)2048 * 2048 * 2);
  u16* Qh  = (u16*)alloc(MK * 2);
  u16* Ql  = (u16*)alloc(MK * 2);
  u16* Kh  = (u16*)alloc((size_t)8192 * 512 * 2);
  u16* Kl  = (u16*)alloc((size_t)8192 * 512 * 2);
  u16* VT  = (u16*)alloc((size_t)8192 * 512 * 2);
  u16* Ch  = (u16*)alloc(MK * 2);
  u16* Cl  = (u16*)alloc(MK * 2);

  conv_split<<<dim3(16384), dim3(256), 0, stream>>>((const float4*)X, Xh, Xl,
                                                    (int)(MK / 4));
  dim3 tb(32, 8);
  transpose_split<<<dim3(64, 64), tb, 0, stream>>>(qw, 2048, 2048, Bth, Btl, 0);
  transpose_split<<<dim3(16, 64), tb, 0, stream>>>(kw, 2048, 512, Bth, Btl, 2048);
  transpose_split<<<dim3(16, 64), tb, 0, stream>>>(vw, 2048, 512, Bth, Btl, 2560);
  transpose_split<<<dim3(64, 64), tb, 0, stream>>>(ow, 2048, 2048, OWh, OWl, 0);
  gemm_split<0><<<dim3(24, 64), dim3(256), 0, stream>>>(
      Xh, Xl, Bth, Btl, 2048, Qh, Ql, Kh, Kl, VT, nullptr, nullptr);
  attn_kernel<<<dim3(512), dim3(512), 0, stream>>>(Qh, Ql, Kh, Kl, VT, Ch, Cl);
  gemm_split<1><<<dim3(16, 64), dim3(256), 0, stream>>>(
      Ch, Cl, OWh, OWl, 2048, nullptr, nullptr, nullptr, nullptr, nullptr, Out, ob);
}

// Round 5
// 668.616 us; speedup vs baseline: 2.0183x; 1.1905x over previous
//
#include <hip/hip_runtime.h>

typedef unsigned short u16;
typedef unsigned int   u32;
typedef __attribute__((ext_vector_type(8))) __bf16 bf16x8;
typedef __attribute__((ext_vector_type(4))) float  f32x4;

#define LOG2E 1.44269504088896340f

__device__ __forceinline__ u16 f2bf(float x) {
  u32 u = __float_as_uint(x);
  u32 r = u + 0x7fffu + ((u >> 16) & 1u);
  return (u16)(r >> 16);
}
__device__ __forceinline__ float bf2f(u16 h) {
  return __uint_as_float(((u32)h) << 16);
}
__device__ __forceinline__ void gload16(const u16* g, u16* l) {
  __builtin_amdgcn_global_load_lds(
      (const __attribute__((address_space(1))) void*)g,
      (__attribute__((address_space(3))) void*)l, 16, 0, 0);
}
__device__ __forceinline__ f32x4 MFMA(bf16x8 a, bf16x8 b, f32x4 c) {
  return __builtin_amdgcn_mfma_f32_16x16x32_bf16(a, b, c, 0, 0, 0);
}
__device__ __forceinline__ float rmax16(float x) {
  x = fmaxf(x, __shfl_xor(x, 1));
  x = fmaxf(x, __shfl_xor(x, 2));
  x = fmaxf(x, __shfl_xor(x, 4));
  x = fmaxf(x, __shfl_xor(x, 8));
  return x;
}
__device__ __forceinline__ float rsum16(float x) {
  x += __shfl_xor(x, 1);
  x += __shfl_xor(x, 2);
  x += __shfl_xor(x, 4);
  x += __shfl_xor(x, 8);
  return x;
}

// ---------------- elementwise fp32 -> bf16 hi/lo split ----------------
__global__ void conv_split(const float4* __restrict__ src,
                           u16* __restrict__ dh, u16* __restrict__ dl, int n4) {
  int i = blockIdx.x * 256 + threadIdx.x;
  if (i >= n4) return;
  float4 v = src[i];
  float a[4] = {v.x, v.y, v.z, v.w};
  union { u16 u[4]; uint2 q; } H, L;
#pragma unroll
  for (int k = 0; k < 4; ++k) {
    u16 hh = f2bf(a[k]);
    H.u[k] = hh;
    L.u[k] = f2bf(a[k] - bf2f(hh));
  }
  *(uint2*)&dh[(size_t)i * 4] = H.q;
  *(uint2*)&dl[(size_t)i * 4] = L.q;
}

// ---------------- transpose [K x N] fp32 -> [N x 2048] bf16 hi/lo ----------------
__global__ void transpose_split(const float* __restrict__ src, int K, int N,
                                u16* __restrict__ dh, u16* __restrict__ dl,
                                int rowOff) {
  __shared__ float t[32][33];
  int n0 = blockIdx.x * 32, k0 = blockIdx.y * 32;
  int tx = threadIdx.x, ty = threadIdx.y;
#pragma unroll
  for (int i = 0; i < 4; ++i)
    t[ty + 8 * i][tx] = src[(size_t)(k0 + ty + 8 * i) * N + n0 + tx];
  __syncthreads();
#pragma unroll
  for (int i = 0; i < 4; ++i) {
    int n = n0 + ty + 8 * i, k = k0 + tx;
    float v = t[tx][ty + 8 * i];
    u16 hh = f2bf(v);
    size_t o = (size_t)(rowOff + n) * 2048 + k;
    dh[o] = hh;
    dl[o] = f2bf(v - bf2f(hh));
  }
}

// ---------------- QKV GEMM: split 3-MFMA, double-buffered, swizzled LDS ----------------
__global__ __launch_bounds__(256) void gemm_qkv(
    const u16* __restrict__ Ah, const u16* __restrict__ Al,
    const u16* __restrict__ Bh, const u16* __restrict__ Bl,
    u16* __restrict__ Qh, u16* __restrict__ Ql,
    u16* __restrict__ Kh, u16* __restrict__ Kl,
    u16* __restrict__ VT) {
  const int K = 2048;
  __shared__ u16 As[2][2][128 * 32];
  __shared__ u16 Bs[2][2][128 * 32];
  int tid = threadIdx.x;
  int l = tid & 63, w = tid >> 6;
  int lr = l & 15, lg = l >> 4;
  int wr = w >> 1, wc = w & 1;
  int rowA = blockIdx.y * 128, colB = blockIdx.x * 128;
  int r0 = tid >> 2;
  // pre-swizzled source slot: physical slot (tid&3) holds logical slot ^ ((row>>1)&3)
  int ssrc = (((tid & 3) ^ ((r0 >> 1) & 3))) * 8;
  const u16* gah = Ah + (size_t)(rowA + r0) * K + ssrc;
  const u16* gal = Al + (size_t)(rowA + r0) * K + ssrc;
  const u16* gbh = Bh + (size_t)(colB + r0) * K + ssrc;
  const u16* gbl = Bl + (size_t)(colB + r0) * K + ssrc;
  size_t half = (size_t)64 * K;
  f32x4 acc[4][4] = {};

  auto STAGE = [&](int kb, int bi) {
    gload16(gah + kb, &As[bi][0][tid * 8]);
    gload16(gah + kb + half, &As[bi][0][(256 + tid) * 8]);
    gload16(gal + kb, &As[bi][1][tid * 8]);
    gload16(gal + kb + half, &As[bi][1][(256 + tid) * 8]);
    gload16(gbh + kb, &Bs[bi][0][tid * 8]);
    gload16(gbh + kb + half, &Bs[bi][0][(256 + tid) * 8]);
    gload16(gbl + kb, &Bs[bi][1][tid * 8]);
    gload16(gbl + kb + half, &Bs[bi][1][(256 + tid) * 8]);
  };

  STAGE(0, 0);
  asm volatile("s_waitcnt vmcnt(0)" ::: "memory");
  __builtin_amdgcn_sched_barrier(0);
  __builtin_amdgcn_s_barrier();
  __builtin_amdgcn_sched_barrier(0);

  int cur = 0;
  int swz = (lr >> 1) & 3;
  for (int kb = 0; kb < K; kb += 32) {
    if (kb + 32 < K) STAGE(kb + 32, cur ^ 1);
    bf16x8 ah[4], al4[4], bh4[4], bl4[4];
#pragma unroll
    for (int i = 0; i < 4; ++i) {
      int rA = (wr * 64 + i * 16 + lr) * 32 + (lg ^ swz) * 8;
      int rB = (wc * 64 + i * 16 + lr) * 32 + (lg ^ swz) * 8;
      ah[i]  = *(const bf16x8*)&As[cur][0][rA];
      al4[i] = *(const bf16x8*)&As[cur][1][rA];
      bh4[i] = *(const bf16x8*)&Bs[cur][0][rB];
      bl4[i] = *(const bf16x8*)&Bs[cur][1][rB];
    }
    __builtin_amdgcn_s_setprio(1);
#pragma unroll
    for (int i = 0; i < 4; ++i)
#pragma unroll
      for (int j = 0; j < 4; ++j) {
        acc[i][j] = MFMA(ah[i], bh4[j], acc[i][j]);
        acc[i][j] = MFMA(al4[i], bh4[j], acc[i][j]);
        acc[i][j] = MFMA(ah[i], bl4[j], acc[i][j]);
      }
    __builtin_amdgcn_s_setprio(0);
    asm volatile("s_waitcnt vmcnt(0) lgkmcnt(0)" ::: "memory");
    __builtin_amdgcn_sched_barrier(0);
    __builtin_amdgcn_s_barrier();
    __builtin_amdgcn_sched_barrier(0);
    cur ^= 1;
  }
#pragma unroll
  for (int i = 0; i < 4; ++i) {
    int row0 = rowA + wr * 64 + i * 16 + lg * 4;
#pragma unroll
    for (int j = 0; j < 4; ++j) {
      int c = colB + wc * 64 + j * 16 + lr;
      f32x4 v = acc[i][j];
      if (c < 2048) {
#pragma unroll
        for (int r = 0; r < 4; ++r) {
          size_t o = (size_t)(row0 + r) * 2048 + c;
          u16 hh = f2bf(v[r]);
          Qh[o] = hh;
          Ql[o] = f2bf(v[r] - bf2f(hh));
        }
      } else if (c < 2560) {
        int ck = c - 2048;
#pragma unroll
        for (int r = 0; r < 4; ++r) {
          size_t o = (size_t)(row0 + r) * 512 + ck;
          u16 hh = f2bf(v[r]);
          Kh[o] = hh;
          Kl[o] = f2bf(v[r] - bf2f(hh));
        }
      } else {
        int cv = c - 2560, kvh = cv >> 7, d = cv & 127;
        int b = row0 >> 11, t = row0 & 2047;
        union { u16 u[4]; uint2 q; } P;
#pragma unroll
        for (int r = 0; r < 4; ++r) P.u[r] = f2bf(v[r]);
        *(uint2*)&VT[((size_t)(b * 4 + kvh) * 128 + d) * 2048 + t] = P.q;
      }
    }
  }
}

// ---------------- out-proj GEMM: plain bf16, double-buffered, swizzled LDS ----------------
__global__ __launch_bounds__(256) void gemm_out(
    const u16* __restrict__ Ah, const u16* __restrict__ Bh,
    float* __restrict__ Out, const float* __restrict__ bias) {
  const int K = 2048;
  __shared__ u16 As[2][128 * 32];
  __shared__ u16 Bs[2][128 * 32];
  int tid = threadIdx.x;
  int l = tid & 63, w = tid >> 6;
  int lr = l & 15, lg = l >> 4;
  int wr = w >> 1, wc = w & 1;
  int rowA = blockIdx.y * 128, colB = blockIdx.x * 128;
  int r0 = tid >> 2;
  int ssrc = (((tid & 3) ^ ((r0 >> 1) & 3))) * 8;
  const u16* gah = Ah + (size_t)(rowA + r0) * K + ssrc;
  const u16* gbh = Bh + (size_t)(colB + r0) * K + ssrc;
  size_t half = (size_t)64 * K;
  f32x4 acc[4][4] = {};

  auto STAGE = [&](int kb, int bi) {
    gload16(gah + kb, &As[bi][tid * 8]);
    gload16(gah + kb + half, &As[bi][(256 + tid) * 8]);
    gload16(gbh + kb, &Bs[bi][tid * 8]);
    gload16(gbh + kb + half, &Bs[bi][(256 + tid) * 8]);
  };

  STAGE(0, 0);
  asm volatile("s_waitcnt vmcnt(0)" ::: "memory");
  __builtin_amdgcn_sched_barrier(0);
  __builtin_amdgcn_s_barrier();
  __builtin_amdgcn_sched_barrier(0);

  int cur = 0;
  int swz = (lr >> 1) & 3;
  for (int kb = 0; kb < K; kb += 32) {
    if (kb + 32 < K) STAGE(kb + 32, cur ^ 1);
    bf16x8 ah[4], bh4[4];
#pragma unroll
    for (int i = 0; i < 4; ++i) {
      ah[i]  = *(const bf16x8*)&As[cur][(wr * 64 + i * 16 + lr) * 32 + (lg ^ swz) * 8];
      bh4[i] = *(const bf16x8*)&Bs[cur][(wc * 64 + i * 16 + lr) * 32 + (lg ^ swz) * 8];
    }
    __builtin_amdgcn_s_setprio(1);
#pragma unroll
    for (int i = 0; i < 4; ++i)
#pragma unroll
      for (int j = 0; j < 4; ++j)
        acc[i][j] = MFMA(ah[i], bh4[j], acc[i][j]);
    __builtin_amdgcn_s_setprio(0);
    asm volatile("s_waitcnt vmcnt(0) lgkmcnt(0)" ::: "memory");
    __builtin_amdgcn_sched_barrier(0);
    __builtin_amdgcn_s_barrier();
    __builtin_amdgcn_sched_barrier(0);
    cur ^= 1;
  }
#pragma unroll
  for (int i = 0; i < 4; ++i) {
    int row0 = rowA + wr * 64 + i * 16 + lg * 4;
#pragma unroll
    for (int j = 0; j < 4; ++j) {
      int c = colB + wc * 64 + j * 16 + lr;
      float bb = bias[c];
#pragma unroll
      for (int r = 0; r < 4; ++r)
        Out[(size_t)(row0 + r) * 2048 + c] = acc[i][j][r] + bb;
    }
  }
}

// ---------------- flash attention v3 (round-3 structure, Ch-only output) ----------------
__global__ __launch_bounds__(512) void attn_kernel(
    const u16* __restrict__ Qh, const u16* __restrict__ Ql,
    const u16* __restrict__ Kh, const u16* __restrict__ Kl,
    const u16* __restrict__ VT,
    u16* __restrict__ Ch) {
  __shared__ u16 Ksh[2][64 * 128];
  __shared__ u16 Ksl[2][64 * 128];
  __shared__ u16 Vs[2][128 * 64];
  __shared__ u16 Ps[8][16 * 64];

  int tid = threadIdx.x;
  int w = tid >> 6, l = tid & 63;
  int lr = l & 15, lg = l >> 4;

  int bid = blockIdx.x;
  int pair = bid & 7;
  int hg = (bid >> 3) & 3;
  int kvh = (bid >> 5) & 3;
  int b = bid >> 7;
  int h = kvh * 4 + hg;

  const u16* Kbh = Kh + (size_t)(b * 2048) * 512 + kvh * 128;
  const u16* Kbl = Kl + (size_t)(b * 2048) * 512 + kvh * 128;
  const u16* Vb  = VT + (size_t)((b * 4 + kvh) * 128) * 2048;
  u16* pw = &Ps[w][0];

  auto STAGE = [&](int t, int bufi) {
    int kv0 = t * 64;
#pragma unroll
    for (int p = 0; p < 2; ++p) {
      int o16 = p * 512 + tid;
      int krow = o16 >> 4;
      int kslot = ((o16 & 15) ^ (krow & 7)) * 8;
      size_t ksrc = (size_t)(kv0 + krow) * 512 + kslot;
      gload16(Kbh + ksrc, &Ksh[bufi][o16 * 8]);
      gload16(Kbl + ksrc, &Ksl[bufi][o16 * 8]);
      int vrow = o16 >> 3;
      int vslot = ((o16 & 7) ^ (vrow & 7)) * 8;
      gload16(Vb + (size_t)vrow * 2048 + kv0 + vslot, &Vs[bufi][o16 * 8]);
    }
  };

  for (int pass = 0; pass < 2; ++pass) {
    int tIdx = pass == 0 ? (15 - pair) : pair;
    int q0 = tIdx * 128;
    int qr0 = q0 + w * 16;
    int nt = q0 / 64 + 2;

    size_t qbase = (size_t)(b * 2048 + qr0 + lr) * 2048 + h * 128 + lg * 8;
    bf16x8 qfh[4], qfl[4];
#pragma unroll
    for (int d = 0; d < 4; ++d) {
      qfh[d] = *(const bf16x8*)(Qh + qbase + d * 32);
      qfl[d] = *(const bf16x8*)(Ql + qbase + d * 32);
    }

    f32x4 o[8] = {};
    float mrun[4] = {-3e38f, -3e38f, -3e38f, -3e38f};
    float lrun[4] = {0.f, 0.f, 0.f, 0.f};

    STAGE(0, 0);
    asm volatile("s_waitcnt vmcnt(0)" ::: "memory");
    __builtin_amdgcn_sched_barrier(0);
    __builtin_amdgcn_s_barrier();
    __builtin_amdgcn_sched_barrier(0);

    int cur = 0;
    for (int t = 0; t < nt; ++t) {
      int kv0 = t * 64;
      if (t + 1 < nt) STAGE(t + 1, cur ^ 1);

      if (kv0 <= qr0 + 15) {
        f32x4 s[4] = {};
        __builtin_amdgcn_s_setprio(1);
#pragma unroll
        for (int d = 0; d < 4; ++d) {
#pragma unroll
          for (int n = 0; n < 4; ++n) {
            int row = n * 16 + lr;
            int sl = ((d * 4 + lg) ^ (row & 7)) * 8;
            bf16x8 kfh = *(const bf16x8*)&Ksh[cur][row * 128 + sl];
            bf16x8 kfl = *(const bf16x8*)&Ksl[cur][row * 128 + sl];
            s[n] = MFMA(qfh[d], kfh, s[n]);
            s[n] = MFMA(qfl[d], kfh, s[n]);
            s[n] = MFMA(qfh[d], kfl, s[n]);
          }
        }
        __builtin_amdgcn_s_setprio(0);
        if (kv0 + 63 > qr0) {
#pragma unroll
          for (int n = 0; n < 4; ++n) {
            int kvi = kv0 + n * 16 + lr;
#pragma unroll
            for (int r = 0; r < 4; ++r)
              if (kvi > qr0 + lg * 4 + r) s[n][r] = -3e38f;
          }
        }
        float tm[4];
#pragma unroll
        for (int r = 0; r < 4; ++r)
          tm[r] = rmax16(fmaxf(fmaxf(s[0][r], s[1][r]), fmaxf(s[2][r], s[3][r])));
        bool grow = (tm[0] > mrun[0]) || (tm[1] > mrun[1]) ||
                    (tm[2] > mrun[2]) || (tm[3] > mrun[3]);
        if (__any(grow)) {
          float alpha[4];
#pragma unroll
          for (int r = 0; r < 4; ++r) {
            float mn = fmaxf(mrun[r], tm[r]);
            alpha[r] = __builtin_amdgcn_exp2f((mrun[r] - mn) * LOG2E);
            mrun[r] = mn;
            lrun[r] *= alpha[r];
          }
#pragma unroll
          for (int dt = 0; dt < 8; ++dt)
#pragma unroll
            for (int r = 0; r < 4; ++r) o[dt][r] *= alpha[r];
        }
        float pv[4][4];
#pragma unroll
        for (int r = 0; r < 4; ++r) {
          float mL = mrun[r] * LOG2E;
          float ps = 0.f;
#pragma unroll
          for (int n = 0; n < 4; ++n) {
            pv[n][r] = __builtin_amdgcn_exp2f(fmaf(s[n][r], LOG2E, -mL));
            ps += pv[n][r];
          }
          lrun[r] += rsum16(ps);
        }
#pragma unroll
        for (int n = 0; n < 4; ++n) {
          int colhi = n * 2 + (lr >> 3);
#pragma unroll
          for (int r = 0; r < 4; ++r) {
            int row = lg * 4 + r;
            pw[row * 64 + ((colhi ^ (row & 7)) * 8) + (lr & 7)] = f2bf(pv[n][r]);
          }
        }
        asm volatile("s_waitcnt lgkmcnt(0)" ::: "memory");
        __builtin_amdgcn_sched_barrier(0);
        __builtin_amdgcn_s_setprio(1);
#pragma unroll
        for (int n2 = 0; n2 < 2; ++n2) {
          bf16x8 pf = *(const bf16x8*)&pw[lr * 64 + (((n2 * 4 + lg) ^ (lr & 7)) * 8)];
#pragma unroll
          for (int dt = 0; dt < 8; ++dt) {
            int d = dt * 16 + lr;
            bf16x8 vf = *(const bf16x8*)&Vs[cur][d * 64 + (((n2 * 4 + lg) ^ (lr & 7)) * 8)];
            o[dt] = MFMA(pf, vf, o[dt]);
          }
        }
        __builtin_amdgcn_s_setprio(0);
      }
      asm volatile("s_waitcnt vmcnt(0) lgkmcnt(0)" ::: "memory");
      __builtin_amdgcn_sched_barrier(0);
      __builtin_amdgcn_s_barrier();
      __builtin_amdgcn_sched_barrier(0);
      cur ^= 1;
    }
#pragma unroll
    for (int dt = 0; dt < 8; ++dt) {
#pragma unroll
      for (int r = 0; r < 4; ++r) {
        float v = o[dt][r] / lrun[r];
        size_t oi = (size_t)(b * 2048 + qr0 + lg * 4 + r) * 2048 + h * 128 + dt * 16 + lr;
        Ch[oi] = f2bf(v);
      }
    }
  }
}

extern "C" void kernel_launch(void* const* d_in, const int* in_sizes, int n_in,
                              void* d_out, int out_size, void* d_ws, size_t ws_size,
                              hipStream_t stream) {
  const float* X  = (const float*)d_in[0];
  const float* qw = (const float*)d_in[1];
  const float* kw = (const float*)d_in[2];
  const float* vw = (const float*)d_in[3];
  const float* ow = (const float*)d_in[4];
  const float* ob = (const float*)d_in[5];
  float* Out = (float*)d_out;

  char* ws = (char*)d_ws;
  size_t off = 0;
  auto alloc = [&](size_t bytes) -> void* {
    void* p = ws + off;
    off += (bytes + 255) & ~(size_t)255;
    return p;
  };
  const size_t MK = (size_t)8192 * 2048;
  u16* Xh  = (u16*)alloc(MK * 2);
  u16* Xl  = (u16*)alloc(MK * 2);
  u16* Bth = (u16*)alloc((size_t)3072 * 2048 * 2);
  u16* Btl = (u16*)alloc((size_t)3072 * 2048 * 2);
  u16* OWh = (u16*)alloc((size_t)2048 * 2048 * 2);
  u16* OWl = (u16*)alloc((size_t)2048 * 2048 * 2);
  u16* Qh  = (u16*)alloc(MK * 2);
  u16* Ql  = (u16*)alloc(MK * 2);
  u16* Kh  = (u16*)alloc((size_t)8192 * 512 * 2);
  u16* Kl  = (u16*)alloc((size_t)8192 * 512 * 2);
  u16* VT  = (u16*)alloc((size_t)8192 * 512 * 2);
  u16* Ch  = (u16*)alloc(MK * 2);

  conv_split<<<dim3(16384), dim3(256), 0, stream>>>((const float4*)X, Xh, Xl,
                                                    (int)(MK / 4));
  dim3 tb(32, 8);
  transpose_split<<<dim3(64, 64), tb, 0, stream>>>(qw, 2048, 2048, Bth, Btl, 0);
  transpose_split<<<dim3(16, 64), tb, 0, stream>>>(kw, 2048, 512, Bth, Btl, 2048);
  transpose_split<<<dim3(16, 64), tb, 0, stream>>>(vw, 2048, 512, Bth, Btl, 2560);
  transpose_split<<<dim3(64, 64), tb, 0, stream>>>(ow, 2048, 2048, OWh, OWl, 0);
  gemm_qkv<<<dim3(24, 64), dim3(256), 0, stream>>>(
      Xh, Xl, Bth, Btl, Qh, Ql, Kh, Kl, VT);
  attn_kernel<<<dim3(512), dim3(512), 0, stream>>>(Qh, Ql, Kh, Kl, VT, Ch);
  gemm_out<<<dim3(16, 64), dim3(256), 0, stream>>>(Ch, OWh, Out, ob);
}

// Round 6
// 460.923 us; speedup vs baseline: 2.9277x; 1.4506x over previous
//
#include <hip/hip_runtime.h>

typedef unsigned short u16;
typedef unsigned int   u32;
typedef __attribute__((ext_vector_type(8))) _Float16 f16x8;
typedef __attribute__((ext_vector_type(4))) float    f32x4;

#define LOG2E 1.44269504088896340f

__device__ __forceinline__ u16 f2h(float x) {
  union { _Float16 h; u16 u; } c;
  c.h = (_Float16)x;
  return c.u;
}
__device__ __forceinline__ void gload16(const u16* g, u16* l) {
  __builtin_amdgcn_global_load_lds(
      (const __attribute__((address_space(1))) void*)g,
      (__attribute__((address_space(3))) void*)l, 16, 0, 0);
}
__device__ __forceinline__ f32x4 MFMA(f16x8 a, f16x8 b, f32x4 c) {
  return __builtin_amdgcn_mfma_f32_16x16x32_f16(a, b, c, 0, 0, 0);
}
__device__ __forceinline__ float rmax16(float x) {
  x = fmaxf(x, __shfl_xor(x, 1));
  x = fmaxf(x, __shfl_xor(x, 2));
  x = fmaxf(x, __shfl_xor(x, 4));
  x = fmaxf(x, __shfl_xor(x, 8));
  return x;
}
__device__ __forceinline__ float rsum16(float x) {
  x += __shfl_xor(x, 1);
  x += __shfl_xor(x, 2);
  x += __shfl_xor(x, 4);
  x += __shfl_xor(x, 8);
  return x;
}

// ---------------- elementwise fp32 -> fp16 ----------------
__global__ void conv_f16(const float4* __restrict__ src, u16* __restrict__ d, int n4) {
  int i = blockIdx.x * 256 + threadIdx.x;
  if (i >= n4) return;
  float4 v = src[i];
  union { u16 u[4]; uint2 q; } H;
  H.u[0] = f2h(v.x); H.u[1] = f2h(v.y); H.u[2] = f2h(v.z); H.u[3] = f2h(v.w);
  *(uint2*)&d[(size_t)i * 4] = H.q;
}

// ---------------- transpose [K x N] fp32 -> [N x 2048] fp16 ----------------
__global__ void transpose_f16(const float* __restrict__ src, int K, int N,
                              u16* __restrict__ d, int rowOff) {
  __shared__ float t[32][33];
  int n0 = blockIdx.x * 32, k0 = blockIdx.y * 32;
  int tx = threadIdx.x, ty = threadIdx.y;
#pragma unroll
  for (int i = 0; i < 4; ++i)
    t[ty + 8 * i][tx] = src[(size_t)(k0 + ty + 8 * i) * N + n0 + tx];
  __syncthreads();
#pragma unroll
  for (int i = 0; i < 4; ++i) {
    int n = n0 + ty + 8 * i, k = k0 + tx;
    d[(size_t)(rowOff + n) * 2048 + k] = f2h(t[tx][ty + 8 * i]);
  }
}

// ---------------- QKV GEMM: fp16 single-MFMA, double-buffered, swizzled LDS ----------------
__global__ __launch_bounds__(256) void gemm_qkv(
    const u16* __restrict__ A, const u16* __restrict__ B,
    u16* __restrict__ Qf, u16* __restrict__ Kf, u16* __restrict__ VT) {
  const int K = 2048;
  __shared__ u16 As[2][128 * 32];
  __shared__ u16 Bs[2][128 * 32];
  int tid = threadIdx.x;
  int l = tid & 63, w = tid >> 6;
  int lr = l & 15, lg = l >> 4;
  int wr = w >> 1, wc = w & 1;
  int rowA = blockIdx.y * 128, colB = blockIdx.x * 128;
  int r0 = tid >> 2;
  // pre-swizzled source slot: physical slot (tid&3) holds logical slot ^ ((row>>1)&3)
  int ssrc = (((tid & 3) ^ ((r0 >> 1) & 3))) * 8;
  const u16* ga = A + (size_t)(rowA + r0) * K + ssrc;
  const u16* gb = B + (size_t)(colB + r0) * K + ssrc;
  size_t half = (size_t)64 * K;
  f32x4 acc[4][4] = {};

  auto STAGE = [&](int kb, int bi) {
    gload16(ga + kb, &As[bi][tid * 8]);
    gload16(ga + kb + half, &As[bi][(256 + tid) * 8]);
    gload16(gb + kb, &Bs[bi][tid * 8]);
    gload16(gb + kb + half, &Bs[bi][(256 + tid) * 8]);
  };

  STAGE(0, 0);
  asm volatile("s_waitcnt vmcnt(0)" ::: "memory");
  __builtin_amdgcn_sched_barrier(0);
  __builtin_amdgcn_s_barrier();
  __builtin_amdgcn_sched_barrier(0);

  int cur = 0;
  int swz = (lr >> 1) & 3;
  for (int kb = 0; kb < K; kb += 32) {
    if (kb + 32 < K) STAGE(kb + 32, cur ^ 1);
    f16x8 ah[4], bh4[4];
#pragma unroll
    for (int i = 0; i < 4; ++i) {
      ah[i]  = *(const f16x8*)&As[cur][(wr * 64 + i * 16 + lr) * 32 + (lg ^ swz) * 8];
      bh4[i] = *(const f16x8*)&Bs[cur][(wc * 64 + i * 16 + lr) * 32 + (lg ^ swz) * 8];
    }
    __builtin_amdgcn_s_setprio(1);
#pragma unroll
    for (int i = 0; i < 4; ++i)
#pragma unroll
      for (int j = 0; j < 4; ++j)
        acc[i][j] = MFMA(ah[i], bh4[j], acc[i][j]);
    __builtin_amdgcn_s_setprio(0);
    asm volatile("s_waitcnt vmcnt(0) lgkmcnt(0)" ::: "memory");
    __builtin_amdgcn_sched_barrier(0);
    __builtin_amdgcn_s_barrier();
    __builtin_amdgcn_sched_barrier(0);
    cur ^= 1;
  }
#pragma unroll
  for (int i = 0; i < 4; ++i) {
    int row0 = rowA + wr * 64 + i * 16 + lg * 4;
#pragma unroll
    for (int j = 0; j < 4; ++j) {
      int c = colB + wc * 64 + j * 16 + lr;
      f32x4 v = acc[i][j];
      if (c < 2048) {
#pragma unroll
        for (int r = 0; r < 4; ++r)
          Qf[(size_t)(row0 + r) * 2048 + c] = f2h(v[r]);
      } else if (c < 2560) {
        int ck = c - 2048;
#pragma unroll
        for (int r = 0; r < 4; ++r)
          Kf[(size_t)(row0 + r) * 512 + ck] = f2h(v[r]);
      } else {
        int cv = c - 2560, kvh = cv >> 7, d = cv & 127;
        int b = row0 >> 11, t = row0 & 2047;
        union { u16 u[4]; uint2 q; } P;
#pragma unroll
        for (int r = 0; r < 4; ++r) P.u[r] = f2h(v[r]);
        *(uint2*)&VT[((size_t)(b * 4 + kvh) * 128 + d) * 2048 + t] = P.q;
      }
    }
  }
}

// ---------------- out-proj GEMM: fp16, double-buffered, swizzled LDS ----------------
__global__ __launch_bounds__(256) void gemm_out(
    const u16* __restrict__ A, const u16* __restrict__ B,
    float* __restrict__ Out, const float* __restrict__ bias) {
  const int K = 2048;
  __shared__ u16 As[2][128 * 32];
  __shared__ u16 Bs[2][128 * 32];
  int tid = threadIdx.x;
  int l = tid & 63, w = tid >> 6;
  int lr = l & 15, lg = l >> 4;
  int wr = w >> 1, wc = w & 1;
  int rowA = blockIdx.y * 128, colB = blockIdx.x * 128;
  int r0 = tid >> 2;
  int ssrc = (((tid & 3) ^ ((r0 >> 1) & 3))) * 8;
  const u16* ga = A + (size_t)(rowA + r0) * K + ssrc;
  const u16* gb = B + (size_t)(colB + r0) * K + ssrc;
  size_t half = (size_t)64 * K;
  f32x4 acc[4][4] = {};

  auto STAGE = [&](int kb, int bi) {
    gload16(ga + kb, &As[bi][tid * 8]);
    gload16(ga + kb + half, &As[bi][(256 + tid) * 8]);
    gload16(gb + kb, &Bs[bi][tid * 8]);
    gload16(gb + kb + half, &Bs[bi][(256 + tid) * 8]);
  };

  STAGE(0, 0);
  asm volatile("s_waitcnt vmcnt(0)" ::: "memory");
  __builtin_amdgcn_sched_barrier(0);
  __builtin_amdgcn_s_barrier();
  __builtin_amdgcn_sched_barrier(0);

  int cur = 0;
  int swz = (lr >> 1) & 3;
  for (int kb = 0; kb < K; kb += 32) {
    if (kb + 32 < K) STAGE(kb + 32, cur ^ 1);
    f16x8 ah[4], bh4[4];
#pragma unroll
    for (int i = 0; i < 4; ++i) {
      ah[i]  = *(const f16x8*)&As[cur][(wr * 64 + i * 16 + lr) * 32 + (lg ^ swz) * 8];
      bh4[i] = *(const f16x8*)&Bs[cur][(wc * 64 + i * 16 + lr) * 32 + (lg ^ swz) * 8];
    }
    __builtin_amdgcn_s_setprio(1);
#pragma unroll
    for (int i = 0; i < 4; ++i)
#pragma unroll
      for (int j = 0; j < 4; ++j)
        acc[i][j] = MFMA(ah[i], bh4[j], acc[i][j]);
    __builtin_amdgcn_s_setprio(0);
    asm volatile("s_waitcnt vmcnt(0) lgkmcnt(0)" ::: "memory");
    __builtin_amdgcn_sched_barrier(0);
    __builtin_amdgcn_s_barrier();
    __builtin_amdgcn_sched_barrier(0);
    cur ^= 1;
  }
#pragma unroll
  for (int i = 0; i < 4; ++i) {
    int row0 = rowA + wr * 64 + i * 16 + lg * 4;
#pragma unroll
    for (int j = 0; j < 4; ++j) {
      int c = colB + wc * 64 + j * 16 + lr;
      float bb = bias[c];
#pragma unroll
      for (int r = 0; r < 4; ++r)
        Out[(size_t)(row0 + r) * 2048 + c] = acc[i][j][r] + bb;
    }
  }
}

// ---------------- flash attention: fp16 single-MFMA, dbuf K/V, uniform work pairing ----------------
__global__ __launch_bounds__(512) void attn_kernel(
    const u16* __restrict__ Qf, const u16* __restrict__ Kf,
    const u16* __restrict__ VT, u16* __restrict__ Ch) {
  __shared__ u16 Ks[2][64 * 128];   // [kv 64][d 128], slot16B ^= (row&7)
  __shared__ u16 Vs[2][128 * 64];   // [d 128][kv 64], slot16B ^= (d&7)
  __shared__ u16 Ps[8][16 * 64];    // per-wave P, slot16B ^= (q&7)

  int tid = threadIdx.x;
  int w = tid >> 6, l = tid & 63;
  int lr = l & 15, lg = l >> 4;

  int bid = blockIdx.x;
  int pair = bid & 7;
  int hg = (bid >> 3) & 3;
  int kvh = (bid >> 5) & 3;
  int b = bid >> 7;
  int h = kvh * 4 + hg;

  const u16* Kb = Kf + (size_t)(b * 2048) * 512 + kvh * 128;
  const u16* Vb = VT + (size_t)((b * 4 + kvh) * 128) * 2048;
  u16* pw = &Ps[w][0];

  auto STAGE = [&](int t, int bufi) {
    int kv0 = t * 64;
#pragma unroll
    for (int p = 0; p < 2; ++p) {
      int o16 = p * 512 + tid;
      int krow = o16 >> 4;
      int kslot = ((o16 & 15) ^ (krow & 7)) * 8;
      gload16(Kb + (size_t)(kv0 + krow) * 512 + kslot, &Ks[bufi][o16 * 8]);
      int vrow = o16 >> 3;
      int vslot = ((o16 & 7) ^ (vrow & 7)) * 8;
      gload16(Vb + (size_t)vrow * 2048 + kv0 + vslot, &Vs[bufi][o16 * 8]);
    }
  };

  for (int pass = 0; pass < 2; ++pass) {
    int tIdx = pass == 0 ? (15 - pair) : pair;
    int q0 = tIdx * 128;
    int qr0 = q0 + w * 16;
    int nt = q0 / 64 + 2;

    size_t qbase = (size_t)(b * 2048 + qr0 + lr) * 2048 + h * 128 + lg * 8;
    f16x8 qf[4];
#pragma unroll
    for (int d = 0; d < 4; ++d)
      qf[d] = *(const f16x8*)(Qf + qbase + d * 32);

    f32x4 o[8] = {};
    float mrun[4] = {-3e38f, -3e38f, -3e38f, -3e38f};
    float lrun[4] = {0.f, 0.f, 0.f, 0.f};

    STAGE(0, 0);
    asm volatile("s_waitcnt vmcnt(0)" ::: "memory");
    __builtin_amdgcn_sched_barrier(0);
    __builtin_amdgcn_s_barrier();
    __builtin_amdgcn_sched_barrier(0);

    int cur = 0;
    for (int t = 0; t < nt; ++t) {
      int kv0 = t * 64;
      if (t + 1 < nt) STAGE(t + 1, cur ^ 1);

      if (kv0 <= qr0 + 15) {
        f32x4 s[4] = {};
        __builtin_amdgcn_s_setprio(1);
#pragma unroll
        for (int d = 0; d < 4; ++d) {
#pragma unroll
          for (int n = 0; n < 4; ++n) {
            int row = n * 16 + lr;
            int sl = ((d * 4 + lg) ^ (row & 7)) * 8;
            f16x8 kf = *(const f16x8*)&Ks[cur][row * 128 + sl];
            s[n] = MFMA(qf[d], kf, s[n]);
          }
        }
        __builtin_amdgcn_s_setprio(0);
        if (kv0 + 63 > qr0) {
#pragma unroll
          for (int n = 0; n < 4; ++n) {
            int kvi = kv0 + n * 16 + lr;
#pragma unroll
            for (int r = 0; r < 4; ++r)
              if (kvi > qr0 + lg * 4 + r) s[n][r] = -3e38f;
          }
        }
        float tm[4];
#pragma unroll
        for (int r = 0; r < 4; ++r)
          tm[r] = rmax16(fmaxf(fmaxf(s[0][r], s[1][r]), fmaxf(s[2][r], s[3][r])));
        bool grow = (tm[0] > mrun[0]) || (tm[1] > mrun[1]) ||
                    (tm[2] > mrun[2]) || (tm[3] > mrun[3]);
        if (__any(grow)) {
          float alpha[4];
#pragma unroll
          for (int r = 0; r < 4; ++r) {
            float mn = fmaxf(mrun[r], tm[r]);
            alpha[r] = __builtin_amdgcn_exp2f((mrun[r] - mn) * LOG2E);
            mrun[r] = mn;
            lrun[r] *= alpha[r];
          }
#pragma unroll
          for (int dt = 0; dt < 8; ++dt)
#pragma unroll
            for (int r = 0; r < 4; ++r) o[dt][r] *= alpha[r];
        }
        float pv[4][4];
#pragma unroll
        for (int r = 0; r < 4; ++r) {
          float mL = mrun[r] * LOG2E;
          float ps = 0.f;
#pragma unroll
          for (int n = 0; n < 4; ++n) {
            pv[n][r] = __builtin_amdgcn_exp2f(fmaf(s[n][r], LOG2E, -mL));
            ps += pv[n][r];
          }
          lrun[r] += rsum16(ps);
        }
#pragma unroll
        for (int n = 0; n < 4; ++n) {
          int colhi = n * 2 + (lr >> 3);
#pragma unroll
          for (int r = 0; r < 4; ++r) {
            int row = lg * 4 + r;
            pw[row * 64 + ((colhi ^ (row & 7)) * 8) + (lr & 7)] = f2h(pv[n][r]);
          }
        }
        asm volatile("s_waitcnt lgkmcnt(0)" ::: "memory");
        __builtin_amdgcn_sched_barrier(0);
        __builtin_amdgcn_s_setprio(1);
#pragma unroll
        for (int n2 = 0; n2 < 2; ++n2) {
          f16x8 pf = *(const f16x8*)&pw[lr * 64 + (((n2 * 4 + lg) ^ (lr & 7)) * 8)];
#pragma unroll
          for (int dt = 0; dt < 8; ++dt) {
            int d = dt * 16 + lr;
            f16x8 vf = *(const f16x8*)&Vs[cur][d * 64 + (((n2 * 4 + lg) ^ (lr & 7)) * 8)];
            o[dt] = MFMA(pf, vf, o[dt]);
          }
        }
        __builtin_amdgcn_s_setprio(0);
      }
      asm volatile("s_waitcnt vmcnt(0) lgkmcnt(0)" ::: "memory");
      __builtin_amdgcn_sched_barrier(0);
      __builtin_amdgcn_s_barrier();
      __builtin_amdgcn_sched_barrier(0);
      cur ^= 1;
    }
#pragma unroll
    for (int dt = 0; dt < 8; ++dt) {
#pragma unroll
      for (int r = 0; r < 4; ++r) {
        float v = o[dt][r] / lrun[r];
        size_t oi = (size_t)(b * 2048 + qr0 + lg * 4 + r) * 2048 + h * 128 + dt * 16 + lr;
        Ch[oi] = f2h(v);
      }
    }
  }
}

extern "C" void kernel_launch(void* const* d_in, const int* in_sizes, int n_in,
                              void* d_out, int out_size, void* d_ws, size_t ws_size,
                              hipStream_t stream) {
  const float* X  = (const float*)d_in[0];
  const float* qw = (const float*)d_in[1];
  const float* kw = (const float*)d_in[2];
  const float* vw = (const float*)d_in[3];
  const float* ow = (const float*)d_in[4];
  const float* ob = (const float*)d_in[5];
  float* Out = (float*)d_out;

  char* ws = (char*)d_ws;
  size_t off = 0;
  auto alloc = [&](size_t bytes) -> void* {
    void* p = ws + off;
    off += (bytes + 255) & ~(size_t)255;
    return p;
  };
  const size_t MK = (size_t)8192 * 2048;
  u16* Xf = (u16*)alloc(MK * 2);
  u16* Bt = (u16*)alloc((size_t)3072 * 2048 * 2);
  u16* OW = (u16*)alloc((size_t)2048 * 2048 * 2);
  u16* Qf = (u16*)alloc(MK * 2);
  u16* Kf = (u16*)alloc((size_t)8192 * 512 * 2);
  u16* VT = (u16*)alloc((size_t)8192 * 512 * 2);
  u16* Ch = (u16*)alloc(MK * 2);

  conv_f16<<<dim3(16384), dim3(256), 0, stream>>>((const float4*)X, Xf, (int)(MK / 4));
  dim3 tb(32, 8);
  transpose_f16<<<dim3(64, 64), tb, 0, stream>>>(qw, 2048, 2048, Bt, 0);
  transpose_f16<<<dim3(16, 64), tb, 0, stream>>>(kw, 2048, 512, Bt, 2048);
  transpose_f16<<<dim3(16, 64), tb, 0, stream>>>(vw, 2048, 512, Bt, 2560);
  transpose_f16<<<dim3(64, 64), tb, 0, stream>>>(ow, 2048, 2048, OW, 0);
  gemm_qkv<<<dim3(24, 64), dim3(256), 0, stream>>>(Xf, Bt, Qf, Kf, VT);
  attn_kernel<<<dim3(512), dim3(512), 0, stream>>>(Qf, Kf, VT, Ch);
  gemm_out<<<dim3(16, 64), dim3(256), 0, stream>>>(Ch, OW, Out, ob);
}

// Round 7
// 453.445 us; speedup vs baseline: 2.9760x; 1.0165x over previous
//
#include <hip/hip_runtime.h>

typedef unsigned short u16;
typedef unsigned int   u32;
typedef __attribute__((ext_vector_type(8))) _Float16 f16x8;
typedef __attribute__((ext_vector_type(4))) float    f32x4;

#define LOG2E 1.44269504088896340f

__device__ __forceinline__ u16 f2h(float x) {
  union { _Float16 h; u16 u; } c;
  c.h = (_Float16)x;
  return c.u;
}
__device__ __forceinline__ void gload16(const u16* g, u16* l) {
  __builtin_amdgcn_global_load_lds(
      (const __attribute__((address_space(1))) void*)g,
      (__attribute__((address_space(3))) void*)l, 16, 0, 0);
}
__device__ __forceinline__ f32x4 MFMA(f16x8 a, f16x8 b, f32x4 c) {
  return __builtin_amdgcn_mfma_f32_16x16x32_f16(a, b, c, 0, 0, 0);
}
__device__ __forceinline__ float rmax16(float x) {
  x = fmaxf(x, __shfl_xor(x, 1));
  x = fmaxf(x, __shfl_xor(x, 2));
  x = fmaxf(x, __shfl_xor(x, 4));
  x = fmaxf(x, __shfl_xor(x, 8));
  return x;
}
__device__ __forceinline__ float rsum16(float x) {
  x += __shfl_xor(x, 1);
  x += __shfl_xor(x, 2);
  x += __shfl_xor(x, 4);
  x += __shfl_xor(x, 8);
  return x;
}

// ---------------- elementwise fp32 -> fp16 ----------------
__global__ void conv_f16(const float4* __restrict__ src, u16* __restrict__ d, int n4) {
  int i = blockIdx.x * 256 + threadIdx.x;
  if (i >= n4) return;
  float4 v = src[i];
  union { u16 u[4]; uint2 q; } H;
  H.u[0] = f2h(v.x); H.u[1] = f2h(v.y); H.u[2] = f2h(v.z); H.u[3] = f2h(v.w);
  *(uint2*)&d[(size_t)i * 4] = H.q;
}

// ---------------- transpose [K x N] fp32 -> [N x 2048] fp16 ----------------
__global__ void transpose_f16(const float* __restrict__ src, int K, int N,
                              u16* __restrict__ d, int rowOff) {
  __shared__ float t[32][33];
  int n0 = blockIdx.x * 32, k0 = blockIdx.y * 32;
  int tx = threadIdx.x, ty = threadIdx.y;
#pragma unroll
  for (int i = 0; i < 4; ++i)
    t[ty + 8 * i][tx] = src[(size_t)(k0 + ty + 8 * i) * N + n0 + tx];
  __syncthreads();
#pragma unroll
  for (int i = 0; i < 4; ++i) {
    int n = n0 + ty + 8 * i, k = k0 + tx;
    d[(size_t)(rowOff + n) * 2048 + k] = f2h(t[tx][ty + 8 * i]);
  }
}

// ---------------- QKV GEMM: fp16 single-MFMA, double-buffered, swizzled LDS ----------------
__global__ __launch_bounds__(256) void gemm_qkv(
    const u16* __restrict__ A, const u16* __restrict__ B,
    u16* __restrict__ Qf, u16* __restrict__ Kf, u16* __restrict__ VT) {
  const int K = 2048;
  __shared__ u16 As[2][128 * 32];
  __shared__ u16 Bs[2][128 * 32];
  int tid = threadIdx.x;
  int l = tid & 63, w = tid >> 6;
  int lr = l & 15, lg = l >> 4;
  int wr = w >> 1, wc = w & 1;
  int rowA = blockIdx.y * 128, colB = blockIdx.x * 128;
  int r0 = tid >> 2;
  int ssrc = (((tid & 3) ^ ((r0 >> 1) & 3))) * 8;
  const u16* ga = A + (size_t)(rowA + r0) * K + ssrc;
  const u16* gb = B + (size_t)(colB + r0) * K + ssrc;
  size_t half = (size_t)64 * K;
  f32x4 acc[4][4] = {};

  auto STAGE = [&](int kb, int bi) {
    gload16(ga + kb, &As[bi][tid * 8]);
    gload16(ga + kb + half, &As[bi][(256 + tid) * 8]);
    gload16(gb + kb, &Bs[bi][tid * 8]);
    gload16(gb + kb + half, &Bs[bi][(256 + tid) * 8]);
  };

  STAGE(0, 0);
  asm volatile("s_waitcnt vmcnt(0)" ::: "memory");
  __builtin_amdgcn_sched_barrier(0);
  __builtin_amdgcn_s_barrier();
  __builtin_amdgcn_sched_barrier(0);

  int cur = 0;
  int swz = (lr >> 1) & 3;
  for (int kb = 0; kb < K; kb += 32) {
    if (kb + 32 < K) STAGE(kb + 32, cur ^ 1);
    f16x8 ah[4], bh4[4];
#pragma unroll
    for (int i = 0; i < 4; ++i) {
      ah[i]  = *(const f16x8*)&As[cur][(wr * 64 + i * 16 + lr) * 32 + (lg ^ swz) * 8];
      bh4[i] = *(const f16x8*)&Bs[cur][(wc * 64 + i * 16 + lr) * 32 + (lg ^ swz) * 8];
    }
    __builtin_amdgcn_s_setprio(1);
#pragma unroll
    for (int i = 0; i < 4; ++i)
#pragma unroll
      for (int j = 0; j < 4; ++j)
        acc[i][j] = MFMA(ah[i], bh4[j], acc[i][j]);
    __builtin_amdgcn_s_setprio(0);
    asm volatile("s_waitcnt vmcnt(0) lgkmcnt(0)" ::: "memory");
    __builtin_amdgcn_sched_barrier(0);
    __builtin_amdgcn_s_barrier();
    __builtin_amdgcn_sched_barrier(0);
    cur ^= 1;
  }
#pragma unroll
  for (int i = 0; i < 4; ++i) {
    int row0 = rowA + wr * 64 + i * 16 + lg * 4;
#pragma unroll
    for (int j = 0; j < 4; ++j) {
      int c = colB + wc * 64 + j * 16 + lr;
      f32x4 v = acc[i][j];
      if (c < 2048) {
#pragma unroll
        for (int r = 0; r < 4; ++r)
          Qf[(size_t)(row0 + r) * 2048 + c] = f2h(v[r]);
      } else if (c < 2560) {
        int ck = c - 2048;
#pragma unroll
        for (int r = 0; r < 4; ++r)
          Kf[(size_t)(row0 + r) * 512 + ck] = f2h(v[r]);
      } else {
        int cv = c - 2560, kvh = cv >> 7, d = cv & 127;
        int b = row0 >> 11, t = row0 & 2047;
        union { u16 u[4]; uint2 q; } P;
#pragma unroll
        for (int r = 0; r < 4; ++r) P.u[r] = f2h(v[r]);
        *(uint2*)&VT[((size_t)(b * 4 + kvh) * 128 + d) * 2048 + t] = P.q;
      }
    }
  }
}

// ---------------- out-proj GEMM: fp16, double-buffered, swizzled LDS ----------------
__global__ __launch_bounds__(256) void gemm_out(
    const u16* __restrict__ A, const u16* __restrict__ B,
    float* __restrict__ Out, const float* __restrict__ bias) {
  const int K = 2048;
  __shared__ u16 As[2][128 * 32];
  __shared__ u16 Bs[2][128 * 32];
  int tid = threadIdx.x;
  int l = tid & 63, w = tid >> 6;
  int lr = l & 15, lg = l >> 4;
  int wr = w >> 1, wc = w & 1;
  int rowA = blockIdx.y * 128, colB = blockIdx.x * 128;
  int r0 = tid >> 2;
  int ssrc = (((tid & 3) ^ ((r0 >> 1) & 3))) * 8;
  const u16* ga = A + (size_t)(rowA + r0) * K + ssrc;
  const u16* gb = B + (size_t)(colB + r0) * K + ssrc;
  size_t half = (size_t)64 * K;
  f32x4 acc[4][4] = {};

  auto STAGE = [&](int kb, int bi) {
    gload16(ga + kb, &As[bi][tid * 8]);
    gload16(ga + kb + half, &As[bi][(256 + tid) * 8]);
    gload16(gb + kb, &Bs[bi][tid * 8]);
    gload16(gb + kb + half, &Bs[bi][(256 + tid) * 8]);
  };

  STAGE(0, 0);
  asm volatile("s_waitcnt vmcnt(0)" ::: "memory");
  __builtin_amdgcn_sched_barrier(0);
  __builtin_amdgcn_s_barrier();
  __builtin_amdgcn_sched_barrier(0);

  int cur = 0;
  int swz = (lr >> 1) & 3;
  for (int kb = 0; kb < K; kb += 32) {
    if (kb + 32 < K) STAGE(kb + 32, cur ^ 1);
    f16x8 ah[4], bh4[4];
#pragma unroll
    for (int i = 0; i < 4; ++i) {
      ah[i]  = *(const f16x8*)&As[cur][(wr * 64 + i * 16 + lr) * 32 + (lg ^ swz) * 8];
      bh4[i] = *(const f16x8*)&Bs[cur][(wc * 64 + i * 16 + lr) * 32 + (lg ^ swz) * 8];
    }
    __builtin_amdgcn_s_setprio(1);
#pragma unroll
    for (int i = 0; i < 4; ++i)
#pragma unroll
      for (int j = 0; j < 4; ++j)
        acc[i][j] = MFMA(ah[i], bh4[j], acc[i][j]);
    __builtin_amdgcn_s_setprio(0);
    asm volatile("s_waitcnt vmcnt(0) lgkmcnt(0)" ::: "memory");
    __builtin_amdgcn_sched_barrier(0);
    __builtin_amdgcn_s_barrier();
    __builtin_amdgcn_sched_barrier(0);
    cur ^= 1;
  }
#pragma unroll
  for (int i = 0; i < 4; ++i) {
    int row0 = rowA + wr * 64 + i * 16 + lg * 4;
#pragma unroll
    for (int j = 0; j < 4; ++j) {
      int c = colB + wc * 64 + j * 16 + lr;
      float bb = bias[c];
#pragma unroll
      for (int r = 0; r < 4; ++r)
        Out[(size_t)(row0 + r) * 2048 + c] = acc[i][j][r] + bb;
    }
  }
}

// ---------------- flash attention v4: 64KB LDS (2 blocks/CU) ----------------
// K double-buffered; V single-buffered with cross-step in-flight staging:
//   step t: [stage K(t+1)] QK^T+softmax | vmcnt(0)+barrier (V(t),K(t+1) ready)
//           | PV | barrier (Vs free) | stage V(t+1) -> drains next step.
__global__ __launch_bounds__(512) void attn_kernel(
    const u16* __restrict__ Qf, const u16* __restrict__ Kf,
    const u16* __restrict__ VT, u16* __restrict__ Ch) {
  __shared__ u16 Ks[2][64 * 128];   // [kv 64][d 128], slot16B ^= (row&7)
  __shared__ u16 Vs[128 * 64];      // [d 128][kv 64], slot16B ^= (d&7)
  __shared__ u16 Ps[8][16 * 64];    // per-wave P, slot16B ^= (q&7)

  int tid = threadIdx.x;
  int w = tid >> 6, l = tid & 63;
  int lr = l & 15, lg = l >> 4;

  int bid = blockIdx.x;
  int pair = bid & 7;
  int hg = (bid >> 3) & 3;
  int kvh = (bid >> 5) & 3;
  int b = bid >> 7;
  int h = kvh * 4 + hg;

  const u16* Kb = Kf + (size_t)(b * 2048) * 512 + kvh * 128;
  const u16* Vb = VT + (size_t)((b * 4 + kvh) * 128) * 2048;
  u16* pw = &Ps[w][0];

  auto STAGE_K = [&](int t, int bufi) {
    int kv0 = t * 64;
#pragma unroll
    for (int p = 0; p < 2; ++p) {
      int o16 = p * 512 + tid;
      int krow = o16 >> 4;
      int kslot = ((o16 & 15) ^ (krow & 7)) * 8;
      gload16(Kb + (size_t)(kv0 + krow) * 512 + kslot, &Ks[bufi][o16 * 8]);
    }
  };
  auto STAGE_V = [&](int t) {
    int kv0 = t * 64;
#pragma unroll
    for (int p = 0; p < 2; ++p) {
      int o16 = p * 512 + tid;
      int vrow = o16 >> 3;
      int vslot = ((o16 & 7) ^ (vrow & 7)) * 8;
      gload16(Vb + (size_t)vrow * 2048 + kv0 + vslot, &Vs[o16 * 8]);
    }
  };

  for (int pass = 0; pass < 2; ++pass) {
    int tIdx = pass == 0 ? (15 - pair) : pair;
    int q0 = tIdx * 128;
    int qr0 = q0 + w * 16;
    int nt = q0 / 64 + 2;

    size_t qbase = (size_t)(b * 2048 + qr0 + lr) * 2048 + h * 128 + lg * 8;
    f16x8 qf[4];
#pragma unroll
    for (int d = 0; d < 4; ++d)
      qf[d] = *(const f16x8*)(Qf + qbase + d * 32);

    f32x4 o[8] = {};
    float mrun[4] = {-3e38f, -3e38f, -3e38f, -3e38f};
    float lrun[4] = {0.f, 0.f, 0.f, 0.f};

    STAGE_K(0, 0);
    STAGE_V(0);
    asm volatile("s_waitcnt vmcnt(0)" ::: "memory");
    __builtin_amdgcn_sched_barrier(0);
    __builtin_amdgcn_s_barrier();
    __builtin_amdgcn_sched_barrier(0);

    int cur = 0;
    for (int t = 0; t < nt; ++t) {
      int kv0 = t * 64;
      bool more = (t + 1 < nt);
      if (more) STAGE_K(t + 1, cur ^ 1);
      bool compute = (kv0 <= qr0 + 15);

      float pv[4][4];
      if (compute) {
        f32x4 s[4] = {};
        __builtin_amdgcn_s_setprio(1);
#pragma unroll
        for (int d = 0; d < 4; ++d) {
#pragma unroll
          for (int n = 0; n < 4; ++n) {
            int row = n * 16 + lr;
            int sl = ((d * 4 + lg) ^ (row & 7)) * 8;
            f16x8 kf = *(const f16x8*)&Ks[cur][row * 128 + sl];
            s[n] = MFMA(qf[d], kf, s[n]);
          }
        }
        __builtin_amdgcn_s_setprio(0);
        if (kv0 + 63 > qr0) {
#pragma unroll
          for (int n = 0; n < 4; ++n) {
            int kvi = kv0 + n * 16 + lr;
#pragma unroll
            for (int r = 0; r < 4; ++r)
              if (kvi > qr0 + lg * 4 + r) s[n][r] = -3e38f;
          }
        }
        float tm[4];
#pragma unroll
        for (int r = 0; r < 4; ++r)
          tm[r] = rmax16(fmaxf(fmaxf(s[0][r], s[1][r]), fmaxf(s[2][r], s[3][r])));
        // defer-max: only rescale when the tile max exceeds running max by >8
        bool grow = (tm[0] > mrun[0] + 8.f) || (tm[1] > mrun[1] + 8.f) ||
                    (tm[2] > mrun[2] + 8.f) || (tm[3] > mrun[3] + 8.f);
        if (__any(grow)) {
          float alpha[4];
#pragma unroll
          for (int r = 0; r < 4; ++r) {
            float mn = fmaxf(mrun[r], tm[r]);
            alpha[r] = __builtin_amdgcn_exp2f((mrun[r] - mn) * LOG2E);
            mrun[r] = mn;
            lrun[r] *= alpha[r];
          }
#pragma unroll
          for (int dt = 0; dt < 8; ++dt)
#pragma unroll
            for (int r = 0; r < 4; ++r) o[dt][r] *= alpha[r];
        }
#pragma unroll
        for (int r = 0; r < 4; ++r) {
          float mL = mrun[r] * LOG2E;
          float ps = 0.f;
#pragma unroll
          for (int n = 0; n < 4; ++n) {
            pv[n][r] = __builtin_amdgcn_exp2f(fmaf(s[n][r], LOG2E, -mL));
            ps += pv[n][r];
          }
          lrun[r] += rsum16(ps);
        }
#pragma unroll
        for (int n = 0; n < 4; ++n) {
          int colhi = n * 2 + (lr >> 3);
#pragma unroll
          for (int r = 0; r < 4; ++r) {
            int row = lg * 4 + r;
            pw[row * 64 + ((colhi ^ (row & 7)) * 8) + (lr & 7)] = f2h(pv[n][r]);
          }
        }
        asm volatile("s_waitcnt lgkmcnt(0)" ::: "memory");
        __builtin_amdgcn_sched_barrier(0);
      }
      // ---- publish V(t) (staged last step) and K(t+1): full drain + barrier
      asm volatile("s_waitcnt vmcnt(0)" ::: "memory");
      __builtin_amdgcn_sched_barrier(0);
      __builtin_amdgcn_s_barrier();
      __builtin_amdgcn_sched_barrier(0);
      if (compute) {
        __builtin_amdgcn_s_setprio(1);
#pragma unroll
        for (int n2 = 0; n2 < 2; ++n2) {
          f16x8 pf = *(const f16x8*)&pw[lr * 64 + (((n2 * 4 + lg) ^ (lr & 7)) * 8)];
#pragma unroll
          for (int dt = 0; dt < 8; ++dt) {
            int d = dt * 16 + lr;
            f16x8 vf = *(const f16x8*)&Vs[d * 64 + (((n2 * 4 + lg) ^ (lr & 7)) * 8)];
            o[dt] = MFMA(pf, vf, o[dt]);
          }
        }
        __builtin_amdgcn_s_setprio(0);
      }
      // ---- all PV reads of Vs complete -> safe to overwrite
      __builtin_amdgcn_s_barrier();
      __builtin_amdgcn_sched_barrier(0);
      if (more) STAGE_V(t + 1);  // in flight across the step boundary
      cur ^= 1;
    }
#pragma unroll
    for (int dt = 0; dt < 8; ++dt) {
#pragma unroll
      for (int r = 0; r < 4; ++r) {
        float v = o[dt][r] / lrun[r];
        size_t oi = (size_t)(b * 2048 + qr0 + lg * 4 + r) * 2048 + h * 128 + dt * 16 + lr;
        Ch[oi] = f2h(v);
      }
    }
  }
}

extern "C" void kernel_launch(void* const* d_in, const int* in_sizes, int n_in,
                              void* d_out, int out_size, void* d_ws, size_t ws_size,
                              hipStream_t stream) {
  const float* X  = (const float*)d_in[0];
  const float* qw = (const float*)d_in[1];
  const float* kw = (const float*)d_in[2];
  const float* vw = (const float*)d_in[3];
  const float* ow = (const float*)d_in[4];
  const float* ob = (const float*)d_in[5];
  float* Out = (float*)d_out;

  char* ws = (char*)d_ws;
  size_t off = 0;
  auto alloc = [&](size_t bytes) -> void* {
    void* p = ws + off;
    off += (bytes + 255) & ~(size_t)255;
    return p;
  };
  const size_t MK = (size_t)8192 * 2048;
  u16* Xf = (u16*)alloc(MK * 2);
  u16* Bt = (u16*)alloc((size_t)3072 * 2048 * 2);
  u16* OW = (u16*)alloc((size_t)2048 * 2048 * 2);
  u16* Qf = (u16*)alloc(MK * 2);
  u16* Kf = (u16*)alloc((size_t)8192 * 512 * 2);
  u16* VT = (u16*)alloc((size_t)8192 * 512 * 2);
  u16* Ch = (u16*)alloc(MK * 2);

  conv_f16<<<dim3(16384), dim3(256), 0, stream>>>((const float4*)X, Xf, (int)(MK / 4));
  dim3 tb(32, 8);
  transpose_f16<<<dim3(64, 64), tb, 0, stream>>>(qw, 2048, 2048, Bt, 0);
  transpose_f16<<<dim3(16, 64), tb, 0, stream>>>(kw, 2048, 512, Bt, 2048);
  transpose_f16<<<dim3(16, 64), tb, 0, stream>>>(vw, 2048, 512, Bt, 2560);
  transpose_f16<<<dim3(64, 64), tb, 0, stream>>>(ow, 2048, 2048, OW, 0);
  gemm_qkv<<<dim3(24, 64), dim3(256), 0, stream>>>(Xf, Bt, Qf, Kf, VT);
  attn_kernel<<<dim3(512), dim3(512), 0, stream>>>(Qf, Kf, VT, Ch);
  gemm_out<<<dim3(16, 64), dim3(256), 0, stream>>>(Ch, OW, Out, ob);
}

// Round 8
// 425.906 us; speedup vs baseline: 3.1684x; 1.0647x over previous
//
#include <hip/hip_runtime.h>

typedef unsigned short u16;
typedef unsigned int   u32;
typedef __attribute__((ext_vector_type(8))) _Float16 f16x8;
typedef __attribute__((ext_vector_type(4))) float    f32x4;

#define LOG2E 1.44269504088896340f

__device__ __forceinline__ u16 f2h(float x) {
  union { _Float16 h; u16 u; } c;
  c.h = (_Float16)x;
  return c.u;
}
__device__ __forceinline__ void gload16(const u16* g, u16* l) {
  __builtin_amdgcn_global_load_lds(
      (const __attribute__((address_space(1))) void*)g,
      (__attribute__((address_space(3))) void*)l, 16, 0, 0);
}
__device__ __forceinline__ f32x4 MFMA(f16x8 a, f16x8 b, f32x4 c) {
  return __builtin_amdgcn_mfma_f32_16x16x32_f16(a, b, c, 0, 0, 0);
}
__device__ __forceinline__ float rmax16(float x) {
  x = fmaxf(x, __shfl_xor(x, 1));
  x = fmaxf(x, __shfl_xor(x, 2));
  x = fmaxf(x, __shfl_xor(x, 4));
  x = fmaxf(x, __shfl_xor(x, 8));
  return x;
}
__device__ __forceinline__ float rsum16(float x) {
  x += __shfl_xor(x, 1);
  x += __shfl_xor(x, 2);
  x += __shfl_xor(x, 4);
  x += __shfl_xor(x, 8);
  return x;
}

// ---------------- elementwise fp32 -> fp16 ----------------
__global__ void conv_f16(const float4* __restrict__ src, u16* __restrict__ d, int n4) {
  int i = blockIdx.x * 256 + threadIdx.x;
  if (i >= n4) return;
  float4 v = src[i];
  union { u16 u[4]; uint2 q; } H;
  H.u[0] = f2h(v.x); H.u[1] = f2h(v.y); H.u[2] = f2h(v.z); H.u[3] = f2h(v.w);
  *(uint2*)&d[(size_t)i * 4] = H.q;
}

// ---------------- transpose [K x N] fp32 -> [N x 2048] fp16 ----------------
__global__ void transpose_f16(const float* __restrict__ src, int K, int N,
                              u16* __restrict__ d, int rowOff) {
  __shared__ float t[32][33];
  int n0 = blockIdx.x * 32, k0 = blockIdx.y * 32;
  int tx = threadIdx.x, ty = threadIdx.y;
#pragma unroll
  for (int i = 0; i < 4; ++i)
    t[ty + 8 * i][tx] = src[(size_t)(k0 + ty + 8 * i) * N + n0 + tx];
  __syncthreads();
#pragma unroll
  for (int i = 0; i < 4; ++i) {
    int n = n0 + ty + 8 * i, k = k0 + tx;
    d[(size_t)(rowOff + n) * 2048 + k] = f2h(t[tx][ty + 8 * i]);
  }
}

// ---------------- QKV GEMM: fp16 single-MFMA, double-buffered, swizzled LDS ----------------
__global__ __launch_bounds__(256) void gemm_qkv(
    const u16* __restrict__ A, const u16* __restrict__ B,
    u16* __restrict__ Qf, u16* __restrict__ Kf, u16* __restrict__ VT) {
  const int K = 2048;
  __shared__ u16 As[2][128 * 32];
  __shared__ u16 Bs[2][128 * 32];
  int tid = threadIdx.x;
  int l = tid & 63, w = tid >> 6;
  int lr = l & 15, lg = l >> 4;
  int wr = w >> 1, wc = w & 1;
  int rowA = blockIdx.y * 128, colB = blockIdx.x * 128;
  int r0 = tid >> 2;
  int ssrc = (((tid & 3) ^ ((r0 >> 1) & 3))) * 8;
  const u16* ga = A + (size_t)(rowA + r0) * K + ssrc;
  const u16* gb = B + (size_t)(colB + r0) * K + ssrc;
  size_t half = (size_t)64 * K;
  f32x4 acc[4][4] = {};

  auto STAGE = [&](int kb, int bi) {
    gload16(ga + kb, &As[bi][tid * 8]);
    gload16(ga + kb + half, &As[bi][(256 + tid) * 8]);
    gload16(gb + kb, &Bs[bi][tid * 8]);
    gload16(gb + kb + half, &Bs[bi][(256 + tid) * 8]);
  };

  STAGE(0, 0);
  asm volatile("s_waitcnt vmcnt(0)" ::: "memory");
  __builtin_amdgcn_sched_barrier(0);
  __builtin_amdgcn_s_barrier();
  __builtin_amdgcn_sched_barrier(0);

  int cur = 0;
  int swz = (lr >> 1) & 3;
  for (int kb = 0; kb < K; kb += 32) {
    if (kb + 32 < K) STAGE(kb + 32, cur ^ 1);
    f16x8 ah[4], bh4[4];
#pragma unroll
    for (int i = 0; i < 4; ++i) {
      ah[i]  = *(const f16x8*)&As[cur][(wr * 64 + i * 16 + lr) * 32 + (lg ^ swz) * 8];
      bh4[i] = *(const f16x8*)&Bs[cur][(wc * 64 + i * 16 + lr) * 32 + (lg ^ swz) * 8];
    }
    __builtin_amdgcn_s_setprio(1);
#pragma unroll
    for (int i = 0; i < 4; ++i)
#pragma unroll
      for (int j = 0; j < 4; ++j)
        acc[i][j] = MFMA(ah[i], bh4[j], acc[i][j]);
    __builtin_amdgcn_s_setprio(0);
    asm volatile("s_waitcnt vmcnt(0) lgkmcnt(0)" ::: "memory");
    __builtin_amdgcn_sched_barrier(0);
    __builtin_amdgcn_s_barrier();
    __builtin_amdgcn_sched_barrier(0);
    cur ^= 1;
  }
#pragma unroll
  for (int i = 0; i < 4; ++i) {
    int row0 = rowA + wr * 64 + i * 16 + lg * 4;
#pragma unroll
    for (int j = 0; j < 4; ++j) {
      int c = colB + wc * 64 + j * 16 + lr;
      f32x4 v = acc[i][j];
      if (c < 2048) {
#pragma unroll
        for (int r = 0; r < 4; ++r)
          Qf[(size_t)(row0 + r) * 2048 + c] = f2h(v[r]);
      } else if (c < 2560) {
        int ck = c - 2048;
#pragma unroll
        for (int r = 0; r < 4; ++r)
          Kf[(size_t)(row0 + r) * 512 + ck] = f2h(v[r]);
      } else {
        int cv = c - 2560, kvh = cv >> 7, d = cv & 127;
        int b = row0 >> 11, t = row0 & 2047;
        union { u16 u[4]; uint2 q; } P;
#pragma unroll
        for (int r = 0; r < 4; ++r) P.u[r] = f2h(v[r]);
        *(uint2*)&VT[((size_t)(b * 4 + kvh) * 128 + d) * 2048 + t] = P.q;
      }
    }
  }
}

// ---------------- out-proj GEMM: fp16, double-buffered, swizzled LDS ----------------
__global__ __launch_bounds__(256) void gemm_out(
    const u16* __restrict__ A, const u16* __restrict__ B,
    float* __restrict__ Out, const float* __restrict__ bias) {
  const int K = 2048;
  __shared__ u16 As[2][128 * 32];
  __shared__ u16 Bs[2][128 * 32];
  int tid = threadIdx.x;
  int l = tid & 63, w = tid >> 6;
  int lr = l & 15, lg = l >> 4;
  int wr = w >> 1, wc = w & 1;
  int rowA = blockIdx.y * 128, colB = blockIdx.x * 128;
  int r0 = tid >> 2;
  int ssrc = (((tid & 3) ^ ((r0 >> 1) & 3))) * 8;
  const u16* ga = A + (size_t)(rowA + r0) * K + ssrc;
  const u16* gb = B + (size_t)(colB + r0) * K + ssrc;
  size_t half = (size_t)64 * K;
  f32x4 acc[4][4] = {};

  auto STAGE = [&](int kb, int bi) {
    gload16(ga + kb, &As[bi][tid * 8]);
    gload16(ga + kb + half, &As[bi][(256 + tid) * 8]);
    gload16(gb + kb, &Bs[bi][tid * 8]);
    gload16(gb + kb + half, &Bs[bi][(256 + tid) * 8]);
  };

  STAGE(0, 0);
  asm volatile("s_waitcnt vmcnt(0)" ::: "memory");
  __builtin_amdgcn_sched_barrier(0);
  __builtin_amdgcn_s_barrier();
  __builtin_amdgcn_sched_barrier(0);

  int cur = 0;
  int swz = (lr >> 1) & 3;
  for (int kb = 0; kb < K; kb += 32) {
    if (kb + 32 < K) STAGE(kb + 32, cur ^ 1);
    f16x8 ah[4], bh4[4];
#pragma unroll
    for (int i = 0; i < 4; ++i) {
      ah[i]  = *(const f16x8*)&As[cur][(wr * 64 + i * 16 + lr) * 32 + (lg ^ swz) * 8];
      bh4[i] = *(const f16x8*)&Bs[cur][(wc * 64 + i * 16 + lr) * 32 + (lg ^ swz) * 8];
    }
    __builtin_amdgcn_s_setprio(1);
#pragma unroll
    for (int i = 0; i < 4; ++i)
#pragma unroll
      for (int j = 0; j < 4; ++j)
        acc[i][j] = MFMA(ah[i], bh4[j], acc[i][j]);
    __builtin_amdgcn_s_setprio(0);
    asm volatile("s_waitcnt vmcnt(0) lgkmcnt(0)" ::: "memory");
    __builtin_amdgcn_sched_barrier(0);
    __builtin_amdgcn_s_barrier();
    __builtin_amdgcn_sched_barrier(0);
    cur ^= 1;
  }
#pragma unroll
  for (int i = 0; i < 4; ++i) {
    int row0 = rowA + wr * 64 + i * 16 + lg * 4;
#pragma unroll
    for (int j = 0; j < 4; ++j) {
      int c = colB + wc * 64 + j * 16 + lr;
      float bb = bias[c];
#pragma unroll
      for (int r = 0; r < 4; ++r)
        Out[(size_t)(row0 + r) * 2048 + c] = acc[i][j][r] + bb;
    }
  }
}

// ---------------- flash attention v5: lean softmax critical path ----------------
// Per-lane partial row-sums (one rsum16 at epilogue); wave-uniform defer-max
// gate (rmax16 only on grow). K dbuf + V single-buffer cross-step staging.
__global__ __launch_bounds__(512) void attn_kernel(
    const u16* __restrict__ Qf, const u16* __restrict__ Kf,
    const u16* __restrict__ VT, u16* __restrict__ Ch) {
  __shared__ u16 Ks[2][64 * 128];   // [kv 64][d 128], slot16B ^= (row&7)
  __shared__ u16 Vs[128 * 64];      // [d 128][kv 64], slot16B ^= (d&7)
  __shared__ u16 Ps[8][16 * 64];    // per-wave P, slot16B ^= (q&7)

  int tid = threadIdx.x;
  int w = tid >> 6, l = tid & 63;
  int lr = l & 15, lg = l >> 4;

  int bid = blockIdx.x;
  int pair = bid & 7;
  int hg = (bid >> 3) & 3;
  int kvh = (bid >> 5) & 3;
  int b = bid >> 7;
  int h = kvh * 4 + hg;

  const u16* Kb = Kf + (size_t)(b * 2048) * 512 + kvh * 128;
  const u16* Vb = VT + (size_t)((b * 4 + kvh) * 128) * 2048;
  u16* pw = &Ps[w][0];

  auto STAGE_K = [&](int t, int bufi) {
    int kv0 = t * 64;
#pragma unroll
    for (int p = 0; p < 2; ++p) {
      int o16 = p * 512 + tid;
      int krow = o16 >> 4;
      int kslot = ((o16 & 15) ^ (krow & 7)) * 8;
      gload16(Kb + (size_t)(kv0 + krow) * 512 + kslot, &Ks[bufi][o16 * 8]);
    }
  };
  auto STAGE_V = [&](int t) {
    int kv0 = t * 64;
#pragma unroll
    for (int p = 0; p < 2; ++p) {
      int o16 = p * 512 + tid;
      int vrow = o16 >> 3;
      int vslot = ((o16 & 7) ^ (vrow & 7)) * 8;
      gload16(Vb + (size_t)vrow * 2048 + kv0 + vslot, &Vs[o16 * 8]);
    }
  };

  for (int pass = 0; pass < 2; ++pass) {
    int tIdx = pass == 0 ? (15 - pair) : pair;
    int q0 = tIdx * 128;
    int qr0 = q0 + w * 16;
    int nt = q0 / 64 + 2;

    size_t qbase = (size_t)(b * 2048 + qr0 + lr) * 2048 + h * 128 + lg * 8;
    f16x8 qf[4];
#pragma unroll
    for (int d = 0; d < 4; ++d)
      qf[d] = *(const f16x8*)(Qf + qbase + d * 32);

    f32x4 o[8] = {};
    float mrun[4] = {-3e38f, -3e38f, -3e38f, -3e38f};
    float lp[4] = {0.f, 0.f, 0.f, 0.f};  // per-lane partial row-sums

    STAGE_K(0, 0);
    STAGE_V(0);
    asm volatile("s_waitcnt vmcnt(0)" ::: "memory");
    __builtin_amdgcn_sched_barrier(0);
    __builtin_amdgcn_s_barrier();
    __builtin_amdgcn_sched_barrier(0);

    int cur = 0;
    for (int t = 0; t < nt; ++t) {
      int kv0 = t * 64;
      bool more = (t + 1 < nt);
      if (more) STAGE_K(t + 1, cur ^ 1);
      bool compute = (kv0 <= qr0 + 15);

      if (compute) {
        f32x4 s[4] = {};
        __builtin_amdgcn_s_setprio(1);
#pragma unroll
        for (int d = 0; d < 4; ++d) {
#pragma unroll
          for (int n = 0; n < 4; ++n) {
            int row = n * 16 + lr;
            int sl = ((d * 4 + lg) ^ (row & 7)) * 8;
            f16x8 kf = *(const f16x8*)&Ks[cur][row * 128 + sl];
            s[n] = MFMA(qf[d], kf, s[n]);
          }
        }
        __builtin_amdgcn_s_setprio(0);
        if (kv0 + 63 > qr0) {
#pragma unroll
          for (int n = 0; n < 4; ++n) {
            int kvi = kv0 + n * 16 + lr;
#pragma unroll
            for (int r = 0; r < 4; ++r)
              if (kvi > qr0 + lg * 4 + r) s[n][r] = -3e38f;
          }
        }
        // ---- gated defer-max: per-lane max only, rmax16 just on grow
        float rowmax[4];
#pragma unroll
        for (int r = 0; r < 4; ++r)
          rowmax[r] = fmaxf(fmaxf(s[0][r], s[1][r]), fmaxf(s[2][r], s[3][r]));
        bool growl = (rowmax[0] > mrun[0] + 8.f) || (rowmax[1] > mrun[1] + 8.f) ||
                     (rowmax[2] > mrun[2] + 8.f) || (rowmax[3] > mrun[3] + 8.f);
        if (__any(growl)) {
          float alpha[4];
#pragma unroll
          for (int r = 0; r < 4; ++r) {
            float tm = rmax16(rowmax[r]);
            float mn = fmaxf(mrun[r], tm);
            alpha[r] = __builtin_amdgcn_exp2f((mrun[r] - mn) * LOG2E);
            mrun[r] = mn;
            lp[r] *= alpha[r];
          }
#pragma unroll
          for (int dt = 0; dt < 8; ++dt)
#pragma unroll
            for (int r = 0; r < 4; ++r) o[dt][r] *= alpha[r];
        }
        float pv[4][4];
#pragma unroll
        for (int r = 0; r < 4; ++r) {
          float mL = mrun[r] * LOG2E;
#pragma unroll
          for (int n = 0; n < 4; ++n) {
            pv[n][r] = __builtin_amdgcn_exp2f(fmaf(s[n][r], LOG2E, -mL));
            lp[r] += pv[n][r];
          }
        }
#pragma unroll
        for (int n = 0; n < 4; ++n) {
          int colhi = n * 2 + (lr >> 3);
#pragma unroll
          for (int r = 0; r < 4; ++r) {
            int row = lg * 4 + r;
            pw[row * 64 + ((colhi ^ (row & 7)) * 8) + (lr & 7)] = f2h(pv[n][r]);
          }
        }
        asm volatile("s_waitcnt lgkmcnt(0)" ::: "memory");
        __builtin_amdgcn_sched_barrier(0);
      }
      // ---- publish V(t) (staged last step) and K(t+1): full drain + barrier
      asm volatile("s_waitcnt vmcnt(0)" ::: "memory");
      __builtin_amdgcn_sched_barrier(0);
      __builtin_amdgcn_s_barrier();
      __builtin_amdgcn_sched_barrier(0);
      if (compute) {
        __builtin_amdgcn_s_setprio(1);
#pragma unroll
        for (int n2 = 0; n2 < 2; ++n2) {
          f16x8 pf = *(const f16x8*)&pw[lr * 64 + (((n2 * 4 + lg) ^ (lr & 7)) * 8)];
#pragma unroll
          for (int dt = 0; dt < 8; ++dt) {
            int d = dt * 16 + lr;
            f16x8 vf = *(const f16x8*)&Vs[d * 64 + (((n2 * 4 + lg) ^ (lr & 7)) * 8)];
            o[dt] = MFMA(pf, vf, o[dt]);
          }
        }
        __builtin_amdgcn_s_setprio(0);
      }
      // ---- all PV reads of Vs complete -> safe to overwrite
      __builtin_amdgcn_s_barrier();
      __builtin_amdgcn_sched_barrier(0);
      if (more) STAGE_V(t + 1);  // in flight across the step boundary
      cur ^= 1;
    }
    // ---- epilogue: one cross-lane sum per row, reciprocal-multiply, store
    float inv[4];
#pragma unroll
    for (int r = 0; r < 4; ++r)
      inv[r] = 1.0f / rsum16(lp[r]);
#pragma unroll
    for (int dt = 0; dt < 8; ++dt) {
#pragma unroll
      for (int r = 0; r < 4; ++r) {
        float v = o[dt][r] * inv[r];
        size_t oi = (size_t)(b * 2048 + qr0 + lg * 4 + r) * 2048 + h * 128 + dt * 16 + lr;
        Ch[oi] = f2h(v);
      }
    }
  }
}

extern "C" void kernel_launch(void* const* d_in, const int* in_sizes, int n_in,
                              void* d_out, int out_size, void* d_ws, size_t ws_size,
                              hipStream_t stream) {
  const float* X  = (const float*)d_in[0];
  const float* qw = (const float*)d_in[1];
  const float* kw = (const float*)d_in[2];
  const float* vw = (const float*)d_in[3];
  const float* ow = (const float*)d_in[4];
  const float* ob = (const float*)d_in[5];
  float* Out = (float*)d_out;

  char* ws = (char*)d_ws;
  size_t off = 0;
  auto alloc = [&](size_t bytes) -> void* {
    void* p = ws + off;
    off += (bytes + 255) & ~(size_t)255;
    return p;
  };
  const size_t MK = (size_t)8192 * 2048;
  u16* Xf = (u16*)alloc(MK * 2);
  u16* Bt = (u16*)alloc((size_t)3072 * 2048 * 2);
  u16* OW = (u16*)alloc((size_t)2048 * 2048 * 2);
  u16* Qf = (u16*)alloc(MK * 2);
  u16* Kf = (u16*)alloc((size_t)8192 * 512 * 2);
  u16* VT = (u16*)alloc((size_t)8192 * 512 * 2);
  u16* Ch = (u16*)alloc(MK * 2);

  conv_f16<<<dim3(16384), dim3(256), 0, stream>>>((const float4*)X, Xf, (int)(MK / 4));
  dim3 tb(32, 8);
  transpose_f16<<<dim3(64, 64), tb, 0, stream>>>(qw, 2048, 2048, Bt, 0);
  transpose_f16<<<dim3(16, 64), tb, 0, stream>>>(kw, 2048, 512, Bt, 2048);
  transpose_f16<<<dim3(16, 64), tb, 0, stream>>>(vw, 2048, 512, Bt, 2560);
  transpose_f16<<<dim3(64, 64), tb, 0, stream>>>(ow, 2048, 2048, OW, 0);
  gemm_qkv<<<dim3(24, 64), dim3(256), 0, stream>>>(Xf, Bt, Qf, Kf, VT);
  attn_kernel<<<dim3(512), dim3(512), 0, stream>>>(Qf, Kf, VT, Ch);
  gemm_out<<<dim3(16, 64), dim3(256), 0, stream>>>(Ch, OW, Out, ob);
}

// Round 10
// 414.750 us; speedup vs baseline: 3.2536x; 1.0269x over previous
//
#include <hip/hip_runtime.h>

typedef unsigned short u16;
typedef unsigned int   u32;
typedef __attribute__((ext_vector_type(8))) _Float16 f16x8;
typedef __attribute__((ext_vector_type(2))) __fp16   fp16x2;
typedef __attribute__((ext_vector_type(4))) float    f32x4;

#define LOG2E 1.44269504088896340f

__device__ __forceinline__ u16 f2h(float x) {
  union { _Float16 h; u16 u; } c;
  c.h = (_Float16)x;
  return c.u;
}
__device__ __forceinline__ u32 pk2(float a, float b) {
  union { fp16x2 h; u32 u; } c;
  c.h = __builtin_amdgcn_cvt_pkrtz(a, b);
  return c.u;
}
__device__ __forceinline__ void swap32(u32& a, u32& b) {
  asm volatile("v_permlane32_swap_b32 %0, %1" : "+v"(a), "+v"(b));
}
__device__ __forceinline__ void swap16(u32& a, u32& b) {
  asm volatile("v_permlane16_swap_b32 %0, %1" : "+v"(a), "+v"(b));
}
__device__ __forceinline__ void gload16(const u16* g, u16* l) {
  __builtin_amdgcn_global_load_lds(
      (const __attribute__((address_space(1))) void*)g,
      (__attribute__((address_space(3))) void*)l, 16, 0, 0);
}
__device__ __forceinline__ f32x4 MFMA(f16x8 a, f16x8 b, f32x4 c) {
  return __builtin_amdgcn_mfma_f32_16x16x32_f16(a, b, c, 0, 0, 0);
}

// ---------------- elementwise fp32 -> fp16 ----------------
__global__ void conv_f16(const float4* __restrict__ src, u16* __restrict__ d, int n4) {
  int i = blockIdx.x * 256 + threadIdx.x;
  if (i >= n4) return;
  float4 v = src[i];
  union { u16 u[4]; uint2 q; } H;
  H.u[0] = f2h(v.x); H.u[1] = f2h(v.y); H.u[2] = f2h(v.z); H.u[3] = f2h(v.w);
  *(uint2*)&d[(size_t)i * 4] = H.q;
}

// ---------------- transpose [K x N] fp32 -> [N x 2048] fp16 ----------------
__global__ void transpose_f16(const float* __restrict__ src, int K, int N,
                              u16* __restrict__ d, int rowOff) {
  __shared__ float t[32][33];
  int n0 = blockIdx.x * 32, k0 = blockIdx.y * 32;
  int tx = threadIdx.x, ty = threadIdx.y;
#pragma unroll
  for (int i = 0; i < 4; ++i)
    t[ty + 8 * i][tx] = src[(size_t)(k0 + ty + 8 * i) * N + n0 + tx];
  __syncthreads();
#pragma unroll
  for (int i = 0; i < 4; ++i) {
    int n = n0 + ty + 8 * i, k = k0 + tx;
    d[(size_t)(rowOff + n) * 2048 + k] = f2h(t[tx][ty + 8 * i]);
  }
}

// ---------------- QKV GEMM: fp16 single-MFMA, double-buffered, swizzled LDS ----------------
__global__ __launch_bounds__(256) void gemm_qkv(
    const u16* __restrict__ A, const u16* __restrict__ B,
    u16* __restrict__ Qf, u16* __restrict__ Kf, u16* __restrict__ VT) {
  const int K = 2048;
  __shared__ u16 As[2][128 * 32];
  __shared__ u16 Bs[2][128 * 32];
  int tid = threadIdx.x;
  int l = tid & 63, w = tid >> 6;
  int lr = l & 15, lg = l >> 4;
  int wr = w >> 1, wc = w & 1;
  int rowA = blockIdx.y * 128, colB = blockIdx.x * 128;
  int r0 = tid >> 2;
  int ssrc = (((tid & 3) ^ ((r0 >> 1) & 3))) * 8;
  const u16* ga = A + (size_t)(rowA + r0) * K + ssrc;
  const u16* gb = B + (size_t)(colB + r0) * K + ssrc;
  size_t half = (size_t)64 * K;
  f32x4 acc[4][4] = {};

  auto STAGE = [&](int kb, int bi) {
    gload16(ga + kb, &As[bi][tid * 8]);
    gload16(ga + kb + half, &As[bi][(256 + tid) * 8]);
    gload16(gb + kb, &Bs[bi][tid * 8]);
    gload16(gb + kb + half, &Bs[bi][(256 + tid) * 8]);
  };

  STAGE(0, 0);
  asm volatile("s_waitcnt vmcnt(0)" ::: "memory");
  __builtin_amdgcn_sched_barrier(0);
  __builtin_amdgcn_s_barrier();
  __builtin_amdgcn_sched_barrier(0);

  int cur = 0;
  int swz = (lr >> 1) & 3;
  for (int kb = 0; kb < K; kb += 32) {
    if (kb + 32 < K) STAGE(kb + 32, cur ^ 1);
    f16x8 ah[4], bh4[4];
#pragma unroll
    for (int i = 0; i < 4; ++i) {
      ah[i]  = *(const f16x8*)&As[cur][(wr * 64 + i * 16 + lr) * 32 + (lg ^ swz) * 8];
      bh4[i] = *(const f16x8*)&Bs[cur][(wc * 64 + i * 16 + lr) * 32 + (lg ^ swz) * 8];
    }
    __builtin_amdgcn_s_setprio(1);
#pragma unroll
    for (int i = 0; i < 4; ++i)
#pragma unroll
      for (int j = 0; j < 4; ++j)
        acc[i][j] = MFMA(ah[i], bh4[j], acc[i][j]);
    __builtin_amdgcn_s_setprio(0);
    asm volatile("s_waitcnt vmcnt(0) lgkmcnt(0)" ::: "memory");
    __builtin_amdgcn_sched_barrier(0);
    __builtin_amdgcn_s_barrier();
    __builtin_amdgcn_sched_barrier(0);
    cur ^= 1;
  }
#pragma unroll
  for (int i = 0; i < 4; ++i) {
    int row0 = rowA + wr * 64 + i * 16 + lg * 4;
#pragma unroll
    for (int j = 0; j < 4; ++j) {
      int c = colB + wc * 64 + j * 16 + lr;
      f32x4 v = acc[i][j];
      if (c < 2048) {
#pragma unroll
        for (int r = 0; r < 4; ++r)
          Qf[(size_t)(row0 + r) * 2048 + c] = f2h(v[r]);
      } else if (c < 2560) {
        int ck = c - 2048;
#pragma unroll
        for (int r = 0; r < 4; ++r)
          Kf[(size_t)(row0 + r) * 512 + ck] = f2h(v[r]);
      } else {
        int cv = c - 2560, kvh = cv >> 7, d = cv & 127;
        int b = row0 >> 11, t = row0 & 2047;
        union { u16 u[4]; uint2 q; } P;
#pragma unroll
        for (int r = 0; r < 4; ++r) P.u[r] = f2h(v[r]);
        *(uint2*)&VT[((size_t)(b * 4 + kvh) * 128 + d) * 2048 + t] = P.q;
      }
    }
  }
}

// ---------------- out-proj GEMM: fp16, double-buffered, swizzled LDS ----------------
__global__ __launch_bounds__(256) void gemm_out(
    const u16* __restrict__ A, const u16* __restrict__ B,
    float* __restrict__ Out, const float* __restrict__ bias) {
  const int K = 2048;
  __shared__ u16 As[2][128 * 32];
  __shared__ u16 Bs[2][128 * 32];
  int tid = threadIdx.x;
  int l = tid & 63, w = tid >> 6;
  int lr = l & 15, lg = l >> 4;
  int wr = w >> 1, wc = w & 1;
  int rowA = blockIdx.y * 128, colB = blockIdx.x * 128;
  int r0 = tid >> 2;
  int ssrc = (((tid & 3) ^ ((r0 >> 1) & 3))) * 8;
  const u16* ga = A + (size_t)(rowA + r0) * K + ssrc;
  const u16* gb = B + (size_t)(colB + r0) * K + ssrc;
  size_t half = (size_t)64 * K;
  f32x4 acc[4][4] = {};

  auto STAGE = [&](int kb, int bi) {
    gload16(ga + kb, &As[bi][tid * 8]);
    gload16(ga + kb + half, &As[bi][(256 + tid) * 8]);
    gload16(gb + kb, &Bs[bi][tid * 8]);
    gload16(gb + kb + half, &Bs[bi][(256 + tid) * 8]);
  };

  STAGE(0, 0);
  asm volatile("s_waitcnt vmcnt(0)" ::: "memory");
  __builtin_amdgcn_sched_barrier(0);
  __builtin_amdgcn_s_barrier();
  __builtin_amdgcn_sched_barrier(0);

  int cur = 0;
  int swz = (lr >> 1) & 3;
  for (int kb = 0; kb < K; kb += 32) {
    if (kb + 32 < K) STAGE(kb + 32, cur ^ 1);
    f16x8 ah[4], bh4[4];
#pragma unroll
    for (int i = 0; i < 4; ++i) {
      ah[i]  = *(const f16x8*)&As[cur][(wr * 64 + i * 16 + lr) * 32 + (lg ^ swz) * 8];
      bh4[i] = *(const f16x8*)&Bs[cur][(wc * 64 + i * 16 + lr) * 32 + (lg ^ swz) * 8];
    }
    __builtin_amdgcn_s_setprio(1);
#pragma unroll
    for (int i = 0; i < 4; ++i)
#pragma unroll
      for (int j = 0; j < 4; ++j)
        acc[i][j] = MFMA(ah[i], bh4[j], acc[i][j]);
    __builtin_amdgcn_s_setprio(0);
    asm volatile("s_waitcnt vmcnt(0) lgkmcnt(0)" ::: "memory");
    __builtin_amdgcn_sched_barrier(0);
    __builtin_amdgcn_s_barrier();
    __builtin_amdgcn_sched_barrier(0);
    cur ^= 1;
  }
#pragma unroll
  for (int i = 0; i < 4; ++i) {
    int row0 = rowA + wr * 64 + i * 16 + lg * 4;
#pragma unroll
    for (int j = 0; j < 4; ++j) {
      int c = colB + wc * 64 + j * 16 + lr;
      float bb = bias[c];
#pragma unroll
      for (int r = 0; r < 4; ++r)
        Out[(size_t)(row0 + r) * 2048 + c] = acc[i][j][r] + bb;
    }
  }
}

// ---------------- flash attention v6: swapped QK^T, in-register P transpose ----------------
// s = mfma(K,Q): lane owns one q-row (q=lr), kv = n*16 + lg*4 + r.
// P -> PV fragment via 8 cvt_pkrtz + 12 permlane swaps (no LDS).
// PV: o = mfma(V, P): lane holds O[q=lr][d = dt*16 + lg*4 + r].
__global__ __launch_bounds__(512) void attn_kernel(
    const u16* __restrict__ Qf, const u16* __restrict__ Kf,
    const u16* __restrict__ VT, u16* __restrict__ Ch) {
  __shared__ u16 Ks[2][64 * 128];   // [kv 64][d 128], slot16B ^= (row&7)
  __shared__ u16 Vs[128 * 64];      // [d 128][kv 64], slot16B ^= (d&7)

  int tid = threadIdx.x;
  int w = tid >> 6, l = tid & 63;
  int lr = l & 15, lg = l >> 4;

  int bid = blockIdx.x;
  int pair = bid & 7;
  int hg = (bid >> 3) & 3;
  int kvh = (bid >> 5) & 3;
  int b = bid >> 7;
  int h = kvh * 4 + hg;

  const u16* Kb = Kf + (size_t)(b * 2048) * 512 + kvh * 128;
  const u16* Vb = VT + (size_t)((b * 4 + kvh) * 128) * 2048;

  auto STAGE_K = [&](int t, int bufi) {
    int kv0 = t * 64;
#pragma unroll
    for (int p = 0; p < 2; ++p) {
      int o16 = p * 512 + tid;
      int krow = o16 >> 4;
      int kslot = ((o16 & 15) ^ (krow & 7)) * 8;
      gload16(Kb + (size_t)(kv0 + krow) * 512 + kslot, &Ks[bufi][o16 * 8]);
    }
  };
  auto STAGE_V = [&](int t) {
    int kv0 = t * 64;
#pragma unroll
    for (int p = 0; p < 2; ++p) {
      int o16 = p * 512 + tid;
      int vrow = o16 >> 3;
      int vslot = ((o16 & 7) ^ (vrow & 7)) * 8;
      gload16(Vb + (size_t)vrow * 2048 + kv0 + vslot, &Vs[o16 * 8]);
    }
  };

  for (int pass = 0; pass < 2; ++pass) {
    int tIdx = pass == 0 ? (15 - pair) : pair;
    int q0 = tIdx * 128;
    int qr0 = q0 + w * 16;
    int nt = q0 / 64 + 2;

    size_t qbase = (size_t)(b * 2048 + qr0 + lr) * 2048 + h * 128 + lg * 8;
    f16x8 qf[4];
#pragma unroll
    for (int d = 0; d < 4; ++d)
      qf[d] = *(const f16x8*)(Qf + qbase + d * 32);

    f32x4 o[8] = {};
    float mrun = -3e38f;
    float lp = 0.f;  // per-lane partial sum of row q=lr

    STAGE_K(0, 0);
    STAGE_V(0);
    asm volatile("s_waitcnt vmcnt(0)" ::: "memory");
    __builtin_amdgcn_sched_barrier(0);
    __builtin_amdgcn_s_barrier();
    __builtin_amdgcn_sched_barrier(0);

    int cur = 0;
    for (int t = 0; t < nt; ++t) {
      int kv0 = t * 64;
      bool more = (t + 1 < nt);
      if (more) STAGE_K(t + 1, cur ^ 1);
      bool compute = (kv0 <= qr0 + 15);

      f16x8 pf0, pf1;
      if (compute) {
        f32x4 s[4] = {};
        __builtin_amdgcn_s_setprio(1);
#pragma unroll
        for (int d = 0; d < 4; ++d) {
#pragma unroll
          for (int n = 0; n < 4; ++n) {
            int row = n * 16 + lr;
            int sl = ((d * 4 + lg) ^ (row & 7)) * 8;
            f16x8 kf = *(const f16x8*)&Ks[cur][row * 128 + sl];
            s[n] = MFMA(kf, qf[d], s[n]);  // swapped: C[kv][q]
          }
        }
        __builtin_amdgcn_s_setprio(0);
        if (kv0 + 63 > qr0) {
#pragma unroll
          for (int n = 0; n < 4; ++n)
#pragma unroll
            for (int r = 0; r < 4; ++r)
              if (kv0 + n * 16 + lg * 4 + r > qr0 + lr) s[n][r] = -3e38f;
        }
        // per-lane rowmax over 16 values (q = lr)
        float m0 = fmaxf(fmaxf(s[0][0], s[0][1]), fmaxf(s[0][2], s[0][3]));
        float m1 = fmaxf(fmaxf(s[1][0], s[1][1]), fmaxf(s[1][2], s[1][3]));
        float m2 = fmaxf(fmaxf(s[2][0], s[2][1]), fmaxf(s[2][2], s[2][3]));
        float m3 = fmaxf(fmaxf(s[3][0], s[3][1]), fmaxf(s[3][2], s[3][3]));
        float rowmax = fmaxf(fmaxf(m0, m1), fmaxf(m2, m3));
        if (__any(rowmax > mrun + 8.f)) {
          float tm = rowmax;
          tm = fmaxf(tm, __shfl_xor(tm, 16));
          tm = fmaxf(tm, __shfl_xor(tm, 32));
          float mn = fmaxf(mrun, tm);
          float alpha = __builtin_amdgcn_exp2f((mrun - mn) * LOG2E);
          mrun = mn;
          lp *= alpha;
#pragma unroll
          for (int dt = 0; dt < 8; ++dt)
#pragma unroll
            for (int r = 0; r < 4; ++r) o[dt][r] *= alpha;
        }
        float mL = mrun * LOG2E;
        float pv[4][4];
#pragma unroll
        for (int n = 0; n < 4; ++n)
#pragma unroll
          for (int r = 0; r < 4; ++r) {
            pv[n][r] = __builtin_amdgcn_exp2f(fmaf(s[n][r], LOG2E, -mL));
            lp += pv[n][r];
          }
        // pack pairs: A0[n] = kv (n*16+lg*4+0,1), A1[n] = (+2,+3)
        u32 A0[4], A1[4];
#pragma unroll
        for (int n = 0; n < 4; ++n) {
          A0[n] = pk2(pv[n][0], pv[n][1]);
          A1[n] = pk2(pv[n][2], pv[n][3]);
        }
        // 3-round lg-group transpose (verified mapping)
        swap32(A0[0], A0[2]); swap32(A0[1], A0[3]);
        swap32(A1[0], A1[2]); swap32(A1[1], A1[3]);
        swap16(A0[0], A0[2]); swap16(A0[1], A0[3]);
        swap16(A1[0], A1[2]); swap16(A1[1], A1[3]);
        swap32(A0[0], A0[1]); swap32(A0[2], A0[3]);
        swap32(A1[0], A1[1]); swap32(A1[2], A1[3]);
        union { u32 w4[4]; f16x8 v; } P0, P1;
        P0.w4[0] = A0[0]; P0.w4[1] = A1[0]; P0.w4[2] = A0[2]; P0.w4[3] = A1[2];
        P1.w4[0] = A0[1]; P1.w4[1] = A1[1]; P1.w4[2] = A0[3]; P1.w4[3] = A1[3];
        pf0 = P0.v;
        pf1 = P1.v;
      }
      // ---- publish V(t) (staged last step) and K(t+1): full drain + barrier
      asm volatile("s_waitcnt vmcnt(0)" ::: "memory");
      __builtin_amdgcn_sched_barrier(0);
      __builtin_amdgcn_s_barrier();
      __builtin_amdgcn_sched_barrier(0);
      if (compute) {
        __builtin_amdgcn_s_setprio(1);
#pragma unroll
        for (int n2 = 0; n2 < 2; ++n2) {
          f16x8 pf = n2 ? pf1 : pf0;
#pragma unroll
          for (int dt = 0; dt < 8; ++dt) {
            int d = dt * 16 + lr;
            f16x8 vf = *(const f16x8*)&Vs[d * 64 + (((n2 * 4 + lg) ^ (lr & 7)) * 8)];
            o[dt] = MFMA(vf, pf, o[dt]);  // C[d][q]: lane holds O[q=lr][d=dt*16+lg*4+r]
          }
        }
        __builtin_amdgcn_s_setprio(0);
      }
      // ---- all PV reads of Vs complete -> safe to overwrite
      __builtin_amdgcn_s_barrier();
      __builtin_amdgcn_sched_barrier(0);
      if (more) STAGE_V(t + 1);  // in flight across the step boundary
      cur ^= 1;
    }
    // ---- epilogue: finish row-sum across lg lanes, normalize, packed store
    lp += __shfl_xor(lp, 16);
    lp += __shfl_xor(lp, 32);
    float inv = 1.0f / lp;
    size_t orow = (size_t)(b * 2048 + qr0 + lr) * 2048 + h * 128 + lg * 4;
#pragma unroll
    for (int dt = 0; dt < 8; ++dt) {
      uint2 pkt;
      pkt.x = pk2(o[dt][0] * inv, o[dt][1] * inv);
      pkt.y = pk2(o[dt][2] * inv, o[dt][3] * inv);
      *(uint2*)&Ch[orow + dt * 16] = pkt;
    }
  }
}

extern "C" void kernel_launch(void* const* d_in, const int* in_sizes, int n_in,
                              void* d_out, int out_size, void* d_ws, size_t ws_size,
                              hipStream_t stream) {
  const float* X  = (const float*)d_in[0];
  const float* qw = (const float*)d_in[1];
  const float* kw = (const float*)d_in[2];
  const float* vw = (const float*)d_in[3];
  const float* ow = (const float*)d_in[4];
  const float* ob = (const float*)d_in[5];
  float* Out = (float*)d_out;

  char* ws = (char*)d_ws;
  size_t off = 0;
  auto alloc = [&](size_t bytes) -> void* {
    void* p = ws + off;
    off += (bytes + 255) & ~(size_t)255;
    return p;
  };
  const size_t MK = (size_t)8192 * 2048;
  u16* Xf = (u16*)alloc(MK * 2);
  u16* Bt = (u16*)alloc((size_t)3072 * 2048 * 2);
  u16* OW = (u16*)alloc((size_t)2048 * 2048 * 2);
  u16* Qf = (u16*)alloc(MK * 2);
  u16* Kf = (u16*)alloc((size_t)8192 * 512 * 2);
  u16* VT = (u16*)alloc((size_t)8192 * 512 * 2);
  u16* Ch = (u16*)alloc(MK * 2);

  conv_f16<<<dim3(16384), dim3(256), 0, stream>>>((const float4*)X, Xf, (int)(MK / 4));
  dim3 tb(32, 8);
  transpose_f16<<<dim3(64, 64), tb, 0, stream>>>(qw, 2048, 2048, Bt, 0);
  transpose_f16<<<dim3(16, 64), tb, 0, stream>>>(kw, 2048, 512, Bt, 2048);
  transpose_f16<<<dim3(16, 64), tb, 0, stream>>>(vw, 2048, 512, Bt, 2560);
  transpose_f16<<<dim3(64, 64), tb, 0, stream>>>(ow, 2048, 2048, OW, 0);
  gemm_qkv<<<dim3(24, 64), dim3(256), 0, stream>>>(Xf, Bt, Qf, Kf, VT);
  attn_kernel<<<dim3(512), dim3(512), 0, stream>>>(Qf, Kf, VT, Ch);
  gemm_out<<<dim3(16, 64), dim3(256), 0, stream>>>(Ch, OW, Out, ob);
}

// Round 11
// 377.388 us; speedup vs baseline: 3.5757x; 1.0990x over previous
//
#include <hip/hip_runtime.h>

typedef unsigned short u16;
typedef unsigned int   u32;
typedef __attribute__((ext_vector_type(8))) _Float16 f16x8;
typedef __attribute__((ext_vector_type(2))) __fp16   fp16x2;
typedef __attribute__((ext_vector_type(4))) float    f32x4;

#define LOG2E 1.44269504088896340f

__device__ __forceinline__ u16 f2h(float x) {
  union { _Float16 h; u16 u; } c;
  c.h = (_Float16)x;
  return c.u;
}
__device__ __forceinline__ u32 pk2(float a, float b) {
  union { fp16x2 h; u32 u; } c;
  c.h = __builtin_amdgcn_cvt_pkrtz(a, b);
  return c.u;
}
__device__ __forceinline__ void swap32(u32& a, u32& b) {
  asm volatile("v_permlane32_swap_b32 %0, %1" : "+v"(a), "+v"(b));
}
__device__ __forceinline__ void swap16(u32& a, u32& b) {
  asm volatile("v_permlane16_swap_b32 %0, %1" : "+v"(a), "+v"(b));
}
__device__ __forceinline__ void gload16(const u16* g, u16* l) {
  __builtin_amdgcn_global_load_lds(
      (const __attribute__((address_space(1))) void*)g,
      (__attribute__((address_space(3))) void*)l, 16, 0, 0);
}
__device__ __forceinline__ f32x4 MFMA(f16x8 a, f16x8 b, f32x4 c) {
  return __builtin_amdgcn_mfma_f32_16x16x32_f16(a, b, c, 0, 0, 0);
}

// ---------------- elementwise fp32 -> fp16 ----------------
__global__ void conv_f16(const float4* __restrict__ src, u16* __restrict__ d, int n4) {
  int i = blockIdx.x * 256 + threadIdx.x;
  if (i >= n4) return;
  float4 v = src[i];
  union { u16 u[4]; uint2 q; } H;
  H.u[0] = f2h(v.x); H.u[1] = f2h(v.y); H.u[2] = f2h(v.z); H.u[3] = f2h(v.w);
  *(uint2*)&d[(size_t)i * 4] = H.q;
}

// ---------------- transpose [K x N] fp32 -> [N x 2048] fp16 ----------------
__global__ void transpose_f16(const float* __restrict__ src, int K, int N,
                              u16* __restrict__ d, int rowOff) {
  __shared__ float t[32][33];
  int n0 = blockIdx.x * 32, k0 = blockIdx.y * 32;
  int tx = threadIdx.x, ty = threadIdx.y;
#pragma unroll
  for (int i = 0; i < 4; ++i)
    t[ty + 8 * i][tx] = src[(size_t)(k0 + ty + 8 * i) * N + n0 + tx];
  __syncthreads();
#pragma unroll
  for (int i = 0; i < 4; ++i) {
    int n = n0 + ty + 8 * i, k = k0 + tx;
    d[(size_t)(rowOff + n) * 2048 + k] = f2h(t[tx][ty + 8 * i]);
  }
}

// ---------------- QKV GEMM: fp16 single-MFMA, double-buffered, swizzled LDS ----------------
__global__ __launch_bounds__(256) void gemm_qkv(
    const u16* __restrict__ A, const u16* __restrict__ B,
    u16* __restrict__ Qf, u16* __restrict__ Kf, u16* __restrict__ VT) {
  const int K = 2048;
  __shared__ u16 As[2][128 * 32];
  __shared__ u16 Bs[2][128 * 32];
  int tid = threadIdx.x;
  int l = tid & 63, w = tid >> 6;
  int lr = l & 15, lg = l >> 4;
  int wr = w >> 1, wc = w & 1;
  int rowA = blockIdx.y * 128, colB = blockIdx.x * 128;
  int r0 = tid >> 2;
  int ssrc = (((tid & 3) ^ ((r0 >> 1) & 3))) * 8;
  const u16* ga = A + (size_t)(rowA + r0) * K + ssrc;
  const u16* gb = B + (size_t)(colB + r0) * K + ssrc;
  size_t half = (size_t)64 * K;
  f32x4 acc[4][4] = {};

  auto STAGE = [&](int kb, int bi) {
    gload16(ga + kb, &As[bi][tid * 8]);
    gload16(ga + kb + half, &As[bi][(256 + tid) * 8]);
    gload16(gb + kb, &Bs[bi][tid * 8]);
    gload16(gb + kb + half, &Bs[bi][(256 + tid) * 8]);
  };

  STAGE(0, 0);
  asm volatile("s_waitcnt vmcnt(0)" ::: "memory");
  __builtin_amdgcn_sched_barrier(0);
  __builtin_amdgcn_s_barrier();
  __builtin_amdgcn_sched_barrier(0);

  int cur = 0;
  int swz = (lr >> 1) & 3;
  for (int kb = 0; kb < K; kb += 32) {
    if (kb + 32 < K) STAGE(kb + 32, cur ^ 1);
    f16x8 ah[4], bh4[4];
#pragma unroll
    for (int i = 0; i < 4; ++i) {
      ah[i]  = *(const f16x8*)&As[cur][(wr * 64 + i * 16 + lr) * 32 + (lg ^ swz) * 8];
      bh4[i] = *(const f16x8*)&Bs[cur][(wc * 64 + i * 16 + lr) * 32 + (lg ^ swz) * 8];
    }
    __builtin_amdgcn_s_setprio(1);
#pragma unroll
    for (int i = 0; i < 4; ++i)
#pragma unroll
      for (int j = 0; j < 4; ++j)
        acc[i][j] = MFMA(ah[i], bh4[j], acc[i][j]);
    __builtin_amdgcn_s_setprio(0);
    asm volatile("s_waitcnt vmcnt(0) lgkmcnt(0)" ::: "memory");
    __builtin_amdgcn_sched_barrier(0);
    __builtin_amdgcn_s_barrier();
    __builtin_amdgcn_sched_barrier(0);
    cur ^= 1;
  }
#pragma unroll
  for (int i = 0; i < 4; ++i) {
    int row0 = rowA + wr * 64 + i * 16 + lg * 4;
#pragma unroll
    for (int j = 0; j < 4; ++j) {
      int c = colB + wc * 64 + j * 16 + lr;
      f32x4 v = acc[i][j];
      if (c < 2048) {
#pragma unroll
        for (int r = 0; r < 4; ++r)
          Qf[(size_t)(row0 + r) * 2048 + c] = f2h(v[r]);
      } else if (c < 2560) {
        int ck = c - 2048;
#pragma unroll
        for (int r = 0; r < 4; ++r)
          Kf[(size_t)(row0 + r) * 512 + ck] = f2h(v[r]);
      } else {
        int cv = c - 2560, kvh = cv >> 7, d = cv & 127;
        int b = row0 >> 11, t = row0 & 2047;
        union { u16 u[4]; uint2 q; } P;
#pragma unroll
        for (int r = 0; r < 4; ++r) P.u[r] = f2h(v[r]);
        *(uint2*)&VT[((size_t)(b * 4 + kvh) * 128 + d) * 2048 + t] = P.q;
      }
    }
  }
}

// ---------------- out-proj GEMM: fp16, double-buffered, swizzled LDS ----------------
__global__ __launch_bounds__(256) void gemm_out(
    const u16* __restrict__ A, const u16* __restrict__ B,
    float* __restrict__ Out, const float* __restrict__ bias) {
  const int K = 2048;
  __shared__ u16 As[2][128 * 32];
  __shared__ u16 Bs[2][128 * 32];
  int tid = threadIdx.x;
  int l = tid & 63, w = tid >> 6;
  int lr = l & 15, lg = l >> 4;
  int wr = w >> 1, wc = w & 1;
  int rowA = blockIdx.y * 128, colB = blockIdx.x * 128;
  int r0 = tid >> 2;
  int ssrc = (((tid & 3) ^ ((r0 >> 1) & 3))) * 8;
  const u16* ga = A + (size_t)(rowA + r0) * K + ssrc;
  const u16* gb = B + (size_t)(colB + r0) * K + ssrc;
  size_t half = (size_t)64 * K;
  f32x4 acc[4][4] = {};

  auto STAGE = [&](int kb, int bi) {
    gload16(ga + kb, &As[bi][tid * 8]);
    gload16(ga + kb + half, &As[bi][(256 + tid) * 8]);
    gload16(gb + kb, &Bs[bi][tid * 8]);
    gload16(gb + kb + half, &Bs[bi][(256 + tid) * 8]);
  };

  STAGE(0, 0);
  asm volatile("s_waitcnt vmcnt(0)" ::: "memory");
  __builtin_amdgcn_sched_barrier(0);
  __builtin_amdgcn_s_barrier();
  __builtin_amdgcn_sched_barrier(0);

  int cur = 0;
  int swz = (lr >> 1) & 3;
  for (int kb = 0; kb < K; kb += 32) {
    if (kb + 32 < K) STAGE(kb + 32, cur ^ 1);
    f16x8 ah[4], bh4[4];
#pragma unroll
    for (int i = 0; i < 4; ++i) {
      ah[i]  = *(const f16x8*)&As[cur][(wr * 64 + i * 16 + lr) * 32 + (lg ^ swz) * 8];
      bh4[i] = *(const f16x8*)&Bs[cur][(wc * 64 + i * 16 + lr) * 32 + (lg ^ swz) * 8];
    }
    __builtin_amdgcn_s_setprio(1);
#pragma unroll
    for (int i = 0; i < 4; ++i)
#pragma unroll
      for (int j = 0; j < 4; ++j)
        acc[i][j] = MFMA(ah[i], bh4[j], acc[i][j]);
    __builtin_amdgcn_s_setprio(0);
    asm volatile("s_waitcnt vmcnt(0) lgkmcnt(0)" ::: "memory");
    __builtin_amdgcn_sched_barrier(0);
    __builtin_amdgcn_s_barrier();
    __builtin_amdgcn_sched_barrier(0);
    cur ^= 1;
  }
#pragma unroll
  for (int i = 0; i < 4; ++i) {
    int row0 = rowA + wr * 64 + i * 16 + lg * 4;
#pragma unroll
    for (int j = 0; j < 4; ++j) {
      int c = colB + wc * 64 + j * 16 + lr;
      float bb = bias[c];
#pragma unroll
      for (int r = 0; r < 4; ++r)
        Out[(size_t)(row0 + r) * 2048 + c] = acc[i][j][r] + bb;
    }
  }
}

// ---------------- flash attention v7: dbuf K+V, ONE barrier per step ----------------
// Per step: stage K/V(t+1) into buf^1, compute QK^T+softmax+transpose+PV on buf,
// then a single vmcnt(0)+barrier. Reads of buf are dep-complete before the
// barrier; buf is rewritten only after every wave passed it -> race-free.
__global__ __launch_bounds__(512) void attn_kernel(
    const u16* __restrict__ Qf, const u16* __restrict__ Kf,
    const u16* __restrict__ VT, u16* __restrict__ Ch) {
  __shared__ u16 Ks[2][64 * 128];   // [kv 64][d 128], slot16B ^= (row&7)
  __shared__ u16 Vs[2][128 * 64];   // [d 128][kv 64], slot16B ^= (d&7)

  int tid = threadIdx.x;
  int w = tid >> 6, l = tid & 63;
  int lr = l & 15, lg = l >> 4;

  int bid = blockIdx.x;
  int pair = bid & 7;
  int hg = (bid >> 3) & 3;
  int kvh = (bid >> 5) & 3;
  int b = bid >> 7;
  int h = kvh * 4 + hg;

  const u16* Kb = Kf + (size_t)(b * 2048) * 512 + kvh * 128;
  const u16* Vb = VT + (size_t)((b * 4 + kvh) * 128) * 2048;

  auto STAGE_K = [&](int t, int bufi) {
    int kv0 = t * 64;
#pragma unroll
    for (int p = 0; p < 2; ++p) {
      int o16 = p * 512 + tid;
      int krow = o16 >> 4;
      int kslot = ((o16 & 15) ^ (krow & 7)) * 8;
      gload16(Kb + (size_t)(kv0 + krow) * 512 + kslot, &Ks[bufi][o16 * 8]);
    }
  };
  auto STAGE_V = [&](int t, int bufi) {
    int kv0 = t * 64;
#pragma unroll
    for (int p = 0; p < 2; ++p) {
      int o16 = p * 512 + tid;
      int vrow = o16 >> 3;
      int vslot = ((o16 & 7) ^ (vrow & 7)) * 8;
      gload16(Vb + (size_t)vrow * 2048 + kv0 + vslot, &Vs[bufi][o16 * 8]);
    }
  };

  for (int pass = 0; pass < 2; ++pass) {
    int tIdx = pass == 0 ? (15 - pair) : pair;
    int q0 = tIdx * 128;
    int qr0 = q0 + w * 16;
    int nt = q0 / 64 + 2;

    size_t qbase = (size_t)(b * 2048 + qr0 + lr) * 2048 + h * 128 + lg * 8;
    f16x8 qf[4];
#pragma unroll
    for (int d = 0; d < 4; ++d)
      qf[d] = *(const f16x8*)(Qf + qbase + d * 32);

    f32x4 o[8] = {};
    float mrun = -3e38f;
    float lp = 0.f;  // per-lane partial sum of row q=lr

    STAGE_K(0, 0);
    STAGE_V(0, 0);
    asm volatile("s_waitcnt vmcnt(0)" ::: "memory");
    __builtin_amdgcn_sched_barrier(0);
    __builtin_amdgcn_s_barrier();
    __builtin_amdgcn_sched_barrier(0);

    int cur = 0;
    for (int t = 0; t < nt; ++t) {
      int kv0 = t * 64;
      bool more = (t + 1 < nt);
      if (more) {
        STAGE_K(t + 1, cur ^ 1);
        STAGE_V(t + 1, cur ^ 1);
      }
      bool compute = (kv0 <= qr0 + 15);

      if (compute) {
        f32x4 s[4] = {};
        __builtin_amdgcn_s_setprio(1);
#pragma unroll
        for (int d = 0; d < 4; ++d) {
#pragma unroll
          for (int n = 0; n < 4; ++n) {
            int row = n * 16 + lr;
            int sl = ((d * 4 + lg) ^ (row & 7)) * 8;
            f16x8 kf = *(const f16x8*)&Ks[cur][row * 128 + sl];
            s[n] = MFMA(kf, qf[d], s[n]);  // swapped: C[kv][q]
          }
        }
        __builtin_amdgcn_s_setprio(0);
        if (kv0 + 63 > qr0) {
#pragma unroll
          for (int n = 0; n < 4; ++n)
#pragma unroll
            for (int r = 0; r < 4; ++r)
              if (kv0 + n * 16 + lg * 4 + r > qr0 + lr) s[n][r] = -3e38f;
        }
        // per-lane rowmax over 16 values (q = lr)
        float m0 = fmaxf(fmaxf(s[0][0], s[0][1]), fmaxf(s[0][2], s[0][3]));
        float m1 = fmaxf(fmaxf(s[1][0], s[1][1]), fmaxf(s[1][2], s[1][3]));
        float m2 = fmaxf(fmaxf(s[2][0], s[2][1]), fmaxf(s[2][2], s[2][3]));
        float m3 = fmaxf(fmaxf(s[3][0], s[3][1]), fmaxf(s[3][2], s[3][3]));
        float rowmax = fmaxf(fmaxf(m0, m1), fmaxf(m2, m3));
        if (__any(rowmax > mrun + 8.f)) {
          float tm = rowmax;
          tm = fmaxf(tm, __shfl_xor(tm, 16));
          tm = fmaxf(tm, __shfl_xor(tm, 32));
          float mn = fmaxf(mrun, tm);
          float alpha = __builtin_amdgcn_exp2f((mrun - mn) * LOG2E);
          mrun = mn;
          lp *= alpha;
#pragma unroll
          for (int dt = 0; dt < 8; ++dt)
#pragma unroll
            for (int r = 0; r < 4; ++r) o[dt][r] *= alpha;
        }
        float mL = mrun * LOG2E;
        float pv[4][4];
#pragma unroll
        for (int n = 0; n < 4; ++n)
#pragma unroll
          for (int r = 0; r < 4; ++r) {
            pv[n][r] = __builtin_amdgcn_exp2f(fmaf(s[n][r], LOG2E, -mL));
            lp += pv[n][r];
          }
        // pack pairs: A0[n] = kv (n*16+lg*4+0,1), A1[n] = (+2,+3)
        u32 A0[4], A1[4];
#pragma unroll
        for (int n = 0; n < 4; ++n) {
          A0[n] = pk2(pv[n][0], pv[n][1]);
          A1[n] = pk2(pv[n][2], pv[n][3]);
        }
        // 3-round lg-group transpose (verified mapping)
        swap32(A0[0], A0[2]); swap32(A0[1], A0[3]);
        swap32(A1[0], A1[2]); swap32(A1[1], A1[3]);
        swap16(A0[0], A0[2]); swap16(A0[1], A0[3]);
        swap16(A1[0], A1[2]); swap16(A1[1], A1[3]);
        swap32(A0[0], A0[1]); swap32(A0[2], A0[3]);
        swap32(A1[0], A1[1]); swap32(A1[2], A1[3]);
        union { u32 w4[4]; f16x8 v; } P0, P1;
        P0.w4[0] = A0[0]; P0.w4[1] = A1[0]; P0.w4[2] = A0[2]; P0.w4[3] = A1[2];
        P1.w4[0] = A0[1]; P1.w4[1] = A1[1]; P1.w4[2] = A0[3]; P1.w4[3] = A1[3];
        __builtin_amdgcn_s_setprio(1);
#pragma unroll
        for (int n2 = 0; n2 < 2; ++n2) {
          f16x8 pf = n2 ? P1.v : P0.v;
#pragma unroll
          for (int dt = 0; dt < 8; ++dt) {
            int d = dt * 16 + lr;
            f16x8 vf = *(const f16x8*)&Vs[cur][d * 64 + (((n2 * 4 + lg) ^ (lr & 7)) * 8)];
            o[dt] = MFMA(vf, pf, o[dt]);  // C[d][q]: lane holds O[q=lr][d=dt*16+lg*4+r]
          }
        }
        __builtin_amdgcn_s_setprio(0);
      }
      // ---- single per-step sync: staging(t+1) landed + compute(t) done
      asm volatile("s_waitcnt vmcnt(0) lgkmcnt(0)" ::: "memory");
      __builtin_amdgcn_sched_barrier(0);
      __builtin_amdgcn_s_barrier();
      __builtin_amdgcn_sched_barrier(0);
      cur ^= 1;
    }
    // ---- epilogue: finish row-sum across lg lanes, normalize, packed store
    lp += __shfl_xor(lp, 16);
    lp += __shfl_xor(lp, 32);
    float inv = 1.0f / lp;
    size_t orow = (size_t)(b * 2048 + qr0 + lr) * 2048 + h * 128 + lg * 4;
#pragma unroll
    for (int dt = 0; dt < 8; ++dt) {
      uint2 pkt;
      pkt.x = pk2(o[dt][0] * inv, o[dt][1] * inv);
      pkt.y = pk2(o[dt][2] * inv, o[dt][3] * inv);
      *(uint2*)&Ch[orow + dt * 16] = pkt;
    }
  }
}

extern "C" void kernel_launch(void* const* d_in, const int* in_sizes, int n_in,
                              void* d_out, int out_size, void* d_ws, size_t ws_size,
                              hipStream_t stream) {
  const float* X  = (const float*)d_in[0];
  const float* qw = (const float*)d_in[1];
  const float* kw = (const float*)d_in[2];
  const float* vw = (const float*)d_in[3];
  const float* ow = (const float*)d_in[4];
  const float* ob = (const float*)d_in[5];
  float* Out = (float*)d_out;

  char* ws = (char*)d_ws;
  size_t off = 0;
  auto alloc = [&](size_t bytes) -> void* {
    void* p = ws + off;
    off += (bytes + 255) & ~(size_t)255;
    return p;
  };
  const size_t MK = (size_t)8192 * 2048;
  u16* Xf = (u16*)alloc(MK * 2);
  u16* Bt = (u16*)alloc((size_t)3072 * 2048 * 2);
  u16* OW = (u16*)alloc((size_t)2048 * 2048 * 2);
  u16* Qf = (u16*)alloc(MK * 2);
  u16* Kf = (u16*)alloc((size_t)8192 * 512 * 2);
  u16* VT = (u16*)alloc((size_t)8192 * 512 * 2);
  u16* Ch = (u16*)alloc(MK * 2);

  conv_f16<<<dim3(16384), dim3(256), 0, stream>>>((const float4*)X, Xf, (int)(MK / 4));
  dim3 tb(32, 8);
  transpose_f16<<<dim3(64, 64), tb, 0, stream>>>(qw, 2048, 2048, Bt, 0);
  transpose_f16<<<dim3(16, 64), tb, 0, stream>>>(kw, 2048, 512, Bt, 2048);
  transpose_f16<<<dim3(16, 64), tb, 0, stream>>>(vw, 2048, 512, Bt, 2560);
  transpose_f16<<<dim3(64, 64), tb, 0, stream>>>(ow, 2048, 2048, OW, 0);
  gemm_qkv<<<dim3(24, 64), dim3(256), 0, stream>>>(Xf, Bt, Qf, Kf, VT);
  attn_kernel<<<dim3(512), dim3(512), 0, stream>>>(Qf, Kf, VT, Ch);
  gemm_out<<<dim3(16, 64), dim3(256), 0, stream>>>(Ch, OW, Out, ob);
}